// Round 1
// baseline (881.786 us; speedup 1.0000x reference)
//
#include <hip/hip_runtime.h>
#include <hip/hip_bf16.h>

#define NEG_SLOPE 0.2f
#define SCAN_TPB 256
#define SCAN_VPT 4
#define SCAN_ELEMS (SCAN_TPB * SCAN_VPT)

static __device__ __forceinline__ unsigned short f2bf(float v) {
    __hip_bfloat16 b = __float2bfloat16(v);
    return *reinterpret_cast<unsigned short*>(&b);
}
static __device__ __forceinline__ float bf2f(unsigned short u) {
    unsigned int x = ((unsigned int)u) << 16;
    return __uint_as_float(x);
}

// ---------------- CSR build ----------------

__global__ void hist_kernel(const int* __restrict__ dst_idx, int* __restrict__ count,
                            int E, int N) {
    int e = blockIdx.x * blockDim.x + threadIdx.x;
    int EN = E + N;
    if (e >= EN) return;
    int d = (e < E) ? dst_idx[e] : (e - E);
    atomicAdd(&count[d], 1);
}

__global__ void scan_blocks_kernel(const int* __restrict__ count, int* __restrict__ local_ex,
                                   int* __restrict__ blockSums, int n) {
    __shared__ int sm[SCAN_TPB];
    int tid = threadIdx.x;
    int base = blockIdx.x * SCAN_ELEMS + tid * SCAN_VPT;
    int v[SCAN_VPT];
    int s = 0;
#pragma unroll
    for (int i = 0; i < SCAN_VPT; i++) {
        v[i] = (base + i < n) ? count[base + i] : 0;
        s += v[i];
    }
    sm[tid] = s;
    __syncthreads();
#pragma unroll
    for (int off = 1; off < SCAN_TPB; off <<= 1) {
        int t = (tid >= off) ? sm[tid - off] : 0;
        __syncthreads();
        sm[tid] += t;
        __syncthreads();
    }
    int ex = sm[tid] - s;  // exclusive prefix of this thread within block
#pragma unroll
    for (int i = 0; i < SCAN_VPT; i++) {
        if (base + i < n) local_ex[base + i] = ex;
        ex += v[i];
    }
    if (tid == SCAN_TPB - 1) blockSums[blockIdx.x] = sm[tid];
}

__global__ void scan_sums_kernel(int* __restrict__ blockSums, int nb) {
    __shared__ int sm[128];
    int tid = threadIdx.x;
    int v = (tid < nb) ? blockSums[tid] : 0;
    sm[tid] = v;
    __syncthreads();
    for (int off = 1; off < 128; off <<= 1) {
        int t = (tid >= off) ? sm[tid - off] : 0;
        __syncthreads();
        sm[tid] += t;
        __syncthreads();
    }
    if (tid < nb) blockSums[tid] = sm[tid] - v;  // exclusive
}

__global__ void scan_finalize_kernel(int* __restrict__ offsets, const int* __restrict__ blockSums,
                                     int* __restrict__ cursor, int n, int total) {
    int tid = threadIdx.x;
    int base = blockIdx.x * SCAN_ELEMS + tid * SCAN_VPT;
    int add = blockSums[blockIdx.x];
#pragma unroll
    for (int i = 0; i < SCAN_VPT; i++) {
        int idx = base + i;
        if (idx < n) {
            int val = offsets[idx] + add;
            offsets[idx] = val;
            cursor[idx] = val;
        }
    }
    if (blockIdx.x == 0 && tid == 0) offsets[n] = total;
}

__global__ void scatter_kernel(const int* __restrict__ src_idx, const int* __restrict__ dst_idx,
                               int* __restrict__ cursor, int* __restrict__ csr_src,
                               int E, int N) {
    int e = blockIdx.x * blockDim.x + threadIdx.x;
    int EN = E + N;
    if (e >= EN) return;
    int s, d;
    if (e < E) {
        s = src_idx[e];
        d = dst_idx[e];
    } else {
        s = d = e - E;
    }
    int pos = atomicAdd(&cursor[d], 1);
    csr_src[pos] = s;
}

// ---------------- Layer 1 GEMM: h1 = x @ W1  (+ attention logits) ----------------
// Tile: 32 rows x 256 cols (full width), BK=32. 256 threads: ty=tid>>5 (8), tx=tid&31.
// Thread computes 4 rows (ty*4+i) x 8 cols (tx*2 + 64*j + p).

__global__ __launch_bounds__(256) void gemm1_kernel(
    const float* __restrict__ x, const float* __restrict__ W1,
    const float* __restrict__ a_src1, const float* __restrict__ a_dst1,
    unsigned short* __restrict__ h1, float* __restrict__ al_src1,
    float* __restrict__ al_dst1, int N) {
    __shared__ float As[32 * 33];
    __shared__ float Bs[32 * 256];

    const int tid = threadIdx.x;
    const int tx = tid & 31, ty = tid >> 5;
    const int m0 = blockIdx.x * 32;

    float acc[4][8];
#pragma unroll
    for (int i = 0; i < 4; i++)
#pragma unroll
        for (int j = 0; j < 8; j++) acc[i][j] = 0.f;

    for (int k0 = 0; k0 < 256; k0 += 32) {
        // stage A: 32 rows x 32 cols, one float4 per thread
        {
            int r = tid >> 3, cg = tid & 7;
            int row = m0 + r;
            if (row >= N) row = N - 1;
            const float4 v = *reinterpret_cast<const float4*>(x + (size_t)row * 256 + k0 + cg * 4);
            As[r * 33 + cg * 4 + 0] = v.x;
            As[r * 33 + cg * 4 + 1] = v.y;
            As[r * 33 + cg * 4 + 2] = v.z;
            As[r * 33 + cg * 4 + 3] = v.w;
        }
        // stage B: W1 rows k0..k0+31 are a contiguous 32KB block
        {
            const float4* src = reinterpret_cast<const float4*>(W1 + (size_t)k0 * 256);
            float4* dstp = reinterpret_cast<float4*>(Bs);
#pragma unroll
            for (int i = 0; i < 8; i++) dstp[tid + i * 256] = src[tid + i * 256];
        }
        __syncthreads();
#pragma unroll
        for (int k = 0; k < 32; k++) {
            float av[4];
#pragma unroll
            for (int i = 0; i < 4; i++) av[i] = As[(ty * 4 + i) * 33 + k];
            float bv[8];
#pragma unroll
            for (int j = 0; j < 4; j++) {
                float2 b = *reinterpret_cast<const float2*>(&Bs[k * 256 + tx * 2 + 64 * j]);
                bv[2 * j] = b.x;
                bv[2 * j + 1] = b.y;
            }
#pragma unroll
            for (int i = 0; i < 4; i++)
#pragma unroll
                for (int jj = 0; jj < 8; jj++) acc[i][jj] += av[i] * bv[jj];
        }
        __syncthreads();
    }

    // epilogue: store h1 (bf16) + attention logits per (row, head)
    float asv[8], adv[8];
#pragma unroll
    for (int j = 0; j < 4; j++) {
        int c = tx * 2 + 64 * j;
        asv[2 * j] = a_src1[c];
        asv[2 * j + 1] = a_src1[c + 1];
        adv[2 * j] = a_dst1[c];
        adv[2 * j + 1] = a_dst1[c + 1];
    }
#pragma unroll
    for (int i = 0; i < 4; i++) {
        int row = m0 + ty * 4 + i;
        bool valid = (row < N);
        if (valid) {
#pragma unroll
            for (int j = 0; j < 4; j++) {
                int c = tx * 2 + 64 * j;
                ushort2 u;
                u.x = f2bf(acc[i][2 * j]);
                u.y = f2bf(acc[i][2 * j + 1]);
                *reinterpret_cast<ushort2*>(h1 + (size_t)row * 256 + c) = u;
            }
        }
        // head 0: j=0,1 (cols<128); head 1: j=2,3
        float ps0 = acc[i][0] * asv[0] + acc[i][1] * asv[1] + acc[i][2] * asv[2] + acc[i][3] * asv[3];
        float pd0 = acc[i][0] * adv[0] + acc[i][1] * adv[1] + acc[i][2] * adv[2] + acc[i][3] * adv[3];
        float ps1 = acc[i][4] * asv[4] + acc[i][5] * asv[5] + acc[i][6] * asv[6] + acc[i][7] * asv[7];
        float pd1 = acc[i][4] * adv[4] + acc[i][5] * adv[5] + acc[i][6] * adv[6] + acc[i][7] * adv[7];
#pragma unroll
        for (int mask = 16; mask >= 1; mask >>= 1) {
            ps0 += __shfl_xor(ps0, mask, 64);
            ps1 += __shfl_xor(ps1, mask, 64);
            pd0 += __shfl_xor(pd0, mask, 64);
            pd1 += __shfl_xor(pd1, mask, 64);
        }
        if (tx == 0 && valid) {
            al_src1[row * 2 + 0] = ps0;
            al_src1[row * 2 + 1] = ps1;
            al_dst1[row * 2 + 0] = pd0;
            al_dst1[row * 2 + 1] = pd1;
        }
    }
}

// ---------------- Layer 1 aggregation (online softmax) + fused layer-2 projection ----------------
// One wave per dst node. lane -> head = lane>>5, channels [lane*4, lane*4+4).

__global__ __launch_bounds__(256) void agg1_kernel(
    const unsigned short* __restrict__ h1,
    const float* __restrict__ al_src1, const float* __restrict__ al_dst1,
    const int* __restrict__ offsets, const int* __restrict__ csr_src,
    const float* __restrict__ b1, const float* __restrict__ W2,
    const float* __restrict__ a_src2, const float* __restrict__ a_dst2,
    float* __restrict__ g2out, float* __restrict__ al_src2o,
    float* __restrict__ al_dst2o, int N) {
    int wid = (blockIdx.x * blockDim.x + threadIdx.x) >> 6;
    if (wid >= N) return;
    int lane = threadIdx.x & 63;
    int head = lane >> 5;
    int ch = lane * 4;

    int beg = offsets[wid], end = offsets[wid + 1];
    float aldv = al_dst1[wid * 2 + head];

    float m = -INFINITY, l = 0.f;
    float a0 = 0.f, a1 = 0.f, a2 = 0.f, a3 = 0.f;
    for (int e = beg; e < end; ++e) {
        int s = csr_src[e];
        float lg = al_src1[s * 2 + head] + aldv;
        lg = (lg > 0.f) ? lg : NEG_SLOPE * lg;
        float mn = fmaxf(m, lg);
        float sc = __expf(m - mn);
        float p = __expf(lg - mn);
        ushort4 hv = *reinterpret_cast<const ushort4*>(h1 + (size_t)s * 256 + ch);
        a0 = a0 * sc + p * bf2f(hv.x);
        a1 = a1 * sc + p * bf2f(hv.y);
        a2 = a2 * sc + p * bf2f(hv.z);
        a3 = a3 * sc + p * bf2f(hv.w);
        l = l * sc + p;
        m = mn;
    }
    float inv = 1.f / l;
    float4 bb = *reinterpret_cast<const float4*>(b1 + ch);
    float r0 = fmaxf(a0 * inv + bb.x, 0.f);
    float r1 = fmaxf(a1 * inv + bb.y, 0.f);
    float r2 = fmaxf(a2 * inv + bb.z, 0.f);
    float r3 = fmaxf(a3 * inv + bb.w, 0.f);

    // fused layer-2 projection: g[c] = sum_k h2[k] * W2[k][c], k distributed over wave
    float4 w0 = *reinterpret_cast<const float4*>(W2 + (size_t)(ch + 0) * 4);
    float4 w1 = *reinterpret_cast<const float4*>(W2 + (size_t)(ch + 1) * 4);
    float4 w2 = *reinterpret_cast<const float4*>(W2 + (size_t)(ch + 2) * 4);
    float4 w3 = *reinterpret_cast<const float4*>(W2 + (size_t)(ch + 3) * 4);
    float g0 = r0 * w0.x + r1 * w1.x + r2 * w2.x + r3 * w3.x;
    float g1 = r0 * w0.y + r1 * w1.y + r2 * w2.y + r3 * w3.y;
    float g2v = r0 * w0.z + r1 * w1.z + r2 * w2.z + r3 * w3.z;
    float g3 = r0 * w0.w + r1 * w1.w + r2 * w2.w + r3 * w3.w;
#pragma unroll
    for (int mask = 32; mask >= 1; mask >>= 1) {
        g0 += __shfl_xor(g0, mask, 64);
        g1 += __shfl_xor(g1, mask, 64);
        g2v += __shfl_xor(g2v, mask, 64);
        g3 += __shfl_xor(g3, mask, 64);
    }
    if (lane == 0) {
        float4 gv;
        gv.x = g0; gv.y = g1; gv.z = g2v; gv.w = g3;
        *reinterpret_cast<float4*>(g2out + (size_t)wid * 4) = gv;
        al_src2o[wid] = g0 * a_src2[0] + g1 * a_src2[1] + g2v * a_src2[2] + g3 * a_src2[3];
        al_dst2o[wid] = g0 * a_dst2[0] + g1 * a_dst2[1] + g2v * a_dst2[2] + g3 * a_dst2[3];
    }
}

// ---------------- Layer 2 aggregation + bias + log_softmax ----------------
// One wave per dst node; all lanes compute redundantly, lane 0 writes.

__global__ __launch_bounds__(256) void agg2_kernel(
    const float* __restrict__ g2, const float* __restrict__ al_src2,
    const float* __restrict__ al_dst2, const int* __restrict__ offsets,
    const int* __restrict__ csr_src, const float* __restrict__ b2,
    float* __restrict__ out, int N) {
    int wid = (blockIdx.x * blockDim.x + threadIdx.x) >> 6;
    if (wid >= N) return;
    int lane = threadIdx.x & 63;

    int beg = offsets[wid], end = offsets[wid + 1];
    float aldv = al_dst2[wid];
    float m = -INFINITY, l = 0.f;
    float a0 = 0.f, a1 = 0.f, a2 = 0.f, a3 = 0.f;
    for (int e = beg; e < end; ++e) {
        int s = csr_src[e];
        float lg = al_src2[s] + aldv;
        lg = (lg > 0.f) ? lg : NEG_SLOPE * lg;
        float mn = fmaxf(m, lg);
        float sc = __expf(m - mn);
        float p = __expf(lg - mn);
        float4 gv = *reinterpret_cast<const float4*>(g2 + (size_t)s * 4);
        a0 = a0 * sc + p * gv.x;
        a1 = a1 * sc + p * gv.y;
        a2 = a2 * sc + p * gv.z;
        a3 = a3 * sc + p * gv.w;
        l = l * sc + p;
        m = mn;
    }
    float inv = 1.f / l;
    float r0 = a0 * inv + b2[0];
    float r1 = a1 * inv + b2[1];
    float r2 = a2 * inv + b2[2];
    float r3 = a3 * inv + b2[3];
    float mx = fmaxf(fmaxf(r0, r1), fmaxf(r2, r3));
    float s0 = __expf(r0 - mx), s1 = __expf(r1 - mx), s2 = __expf(r2 - mx), s3 = __expf(r3 - mx);
    float ls = __logf(s0 + s1 + s2 + s3);
    if (lane == 0) {
        float4 ov;
        ov.x = r0 - mx - ls;
        ov.y = r1 - mx - ls;
        ov.z = r2 - mx - ls;
        ov.w = r3 - mx - ls;
        *reinterpret_cast<float4*>(out + (size_t)wid * 4) = ov;
    }
}

// ---------------- host ----------------

extern "C" void kernel_launch(void* const* d_in, const int* in_sizes, int n_in,
                              void* d_out, int out_size, void* d_ws, size_t ws_size,
                              hipStream_t stream) {
    const float* x = (const float*)d_in[0];
    const int* edge_index = (const int*)d_in[1];
    const float* W1 = (const float*)d_in[2];
    const float* a_src1 = (const float*)d_in[3];
    const float* a_dst1 = (const float*)d_in[4];
    const float* b1 = (const float*)d_in[5];
    const float* W2 = (const float*)d_in[6];
    const float* a_src2 = (const float*)d_in[7];
    const float* a_dst2 = (const float*)d_in[8];
    const float* b2 = (const float*)d_in[9];
    float* out = (float*)d_out;

    const int N = in_sizes[0] / 256;
    const int E = in_sizes[1] / 2;
    const int EN = E + N;
    const int* src_idx = edge_index;
    const int* dst_idx = edge_index + E;

    char* ws = (char*)d_ws;
    size_t off = 0;
    auto alloc = [&](size_t bytes) -> char* {
        char* p = ws + off;
        off += (bytes + 255) & ~(size_t)255;
        return p;
    };
    unsigned short* h1 = (unsigned short*)alloc((size_t)N * 256 * 2);
    float* al_src1 = (float*)alloc((size_t)N * 2 * 4);
    float* al_dst1 = (float*)alloc((size_t)N * 2 * 4);
    float* g2 = (float*)alloc((size_t)N * 4 * 4);
    float* al_src2 = (float*)alloc((size_t)N * 4);
    float* al_dst2 = (float*)alloc((size_t)N * 4);
    int* offsets = (int*)alloc((size_t)(N + 1) * 4);
    int* cursor = (int*)alloc((size_t)N * 4);
    int* csr_src = (int*)alloc((size_t)EN * 4);
    int* blockSums = (int*)alloc(128 * 4);

    hipMemsetAsync(cursor, 0, (size_t)N * 4, stream);

    int hb = (EN + 255) / 256;
    hist_kernel<<<hb, 256, 0, stream>>>(dst_idx, cursor, E, N);

    int nb = (N + SCAN_ELEMS - 1) / SCAN_ELEMS;  // 98 for N=100000 (must be <=128)
    scan_blocks_kernel<<<nb, SCAN_TPB, 0, stream>>>(cursor, offsets, blockSums, N);
    scan_sums_kernel<<<1, 128, 0, stream>>>(blockSums, nb);
    scan_finalize_kernel<<<nb, SCAN_TPB, 0, stream>>>(offsets, blockSums, cursor, N, EN);

    scatter_kernel<<<hb, 256, 0, stream>>>(src_idx, dst_idx, cursor, csr_src, E, N);

    int gb = (N + 31) / 32;
    gemm1_kernel<<<gb, 256, 0, stream>>>(x, W1, a_src1, a_dst1, h1, al_src1, al_dst1, N);

    int ab = (N + 3) / 4;  // 4 waves (nodes) per 256-thread block
    agg1_kernel<<<ab, 256, 0, stream>>>(h1, al_src1, al_dst1, offsets, csr_src, b1, W2,
                                        a_src2, a_dst2, g2, al_src2, al_dst2, N);
    agg2_kernel<<<ab, 256, 0, stream>>>(g2, al_src2, al_dst2, offsets, csr_src, b2, out, N);
}

// Round 5
// 704.587 us; speedup vs baseline: 1.2515x; 1.2515x over previous
//
#include <hip/hip_runtime.h>
#include <hip/hip_bf16.h>

#define NEG_SLOPE 0.2f
#define SCAN_TPB 256
#define SCAN_VPT 4
#define SCAN_ELEMS (SCAN_TPB * SCAN_VPT)

typedef __attribute__((ext_vector_type(8))) short short8;
typedef __attribute__((ext_vector_type(4))) float f32x4;

static __device__ __forceinline__ unsigned short f2bf(float v) {
    __hip_bfloat16 b = __float2bfloat16(v);
    return *reinterpret_cast<unsigned short*>(&b);
}
static __device__ __forceinline__ float bf2f(unsigned short u) {
    unsigned int x = ((unsigned int)u) << 16;
    return __uint_as_float(x);
}

// ---------------- CSR build ----------------

__global__ void hist_kernel(const int* __restrict__ dst_idx, int* __restrict__ count,
                            int E, int N) {
    int e = blockIdx.x * blockDim.x + threadIdx.x;
    int EN = E + N;
    if (e >= EN) return;
    int d = (e < E) ? dst_idx[e] : (e - E);
    atomicAdd(&count[d], 1);
}

__global__ void scan_blocks_kernel(const int* __restrict__ count, int* __restrict__ local_ex,
                                   int* __restrict__ blockSums, int n) {
    __shared__ int sm[SCAN_TPB];
    int tid = threadIdx.x;
    int base = blockIdx.x * SCAN_ELEMS + tid * SCAN_VPT;
    int v[SCAN_VPT];
    int s = 0;
#pragma unroll
    for (int i = 0; i < SCAN_VPT; i++) {
        v[i] = (base + i < n) ? count[base + i] : 0;
        s += v[i];
    }
    sm[tid] = s;
    __syncthreads();
#pragma unroll
    for (int off = 1; off < SCAN_TPB; off <<= 1) {
        int t = (tid >= off) ? sm[tid - off] : 0;
        __syncthreads();
        sm[tid] += t;
        __syncthreads();
    }
    int ex = sm[tid] - s;
#pragma unroll
    for (int i = 0; i < SCAN_VPT; i++) {
        if (base + i < n) local_ex[base + i] = ex;
        ex += v[i];
    }
    if (tid == SCAN_TPB - 1) blockSums[blockIdx.x] = sm[tid];
}

__global__ void scan_sums_kernel(int* __restrict__ blockSums, int nb) {
    __shared__ int sm[128];
    int tid = threadIdx.x;
    int v = (tid < nb) ? blockSums[tid] : 0;
    sm[tid] = v;
    __syncthreads();
    for (int off = 1; off < 128; off <<= 1) {
        int t = (tid >= off) ? sm[tid - off] : 0;
        __syncthreads();
        sm[tid] += t;
        __syncthreads();
    }
    if (tid < nb) blockSums[tid] = sm[tid] - v;
}

__global__ void scan_finalize_kernel(int* __restrict__ offsets, const int* __restrict__ blockSums,
                                     int* __restrict__ cursor, int n, int total) {
    int tid = threadIdx.x;
    int base = blockIdx.x * SCAN_ELEMS + tid * SCAN_VPT;
    int add = blockSums[blockIdx.x];
#pragma unroll
    for (int i = 0; i < SCAN_VPT; i++) {
        int idx = base + i;
        if (idx < n) {
            int val = offsets[idx] + add;
            offsets[idx] = val;
            cursor[idx] = val;
        }
    }
    if (blockIdx.x == 0 && tid == 0) offsets[n] = total;
}

__global__ void scatter_kernel(const int* __restrict__ src_idx, const int* __restrict__ dst_idx,
                               int* __restrict__ cursor, int* __restrict__ csr_src,
                               int E, int N) {
    int e = blockIdx.x * blockDim.x + threadIdx.x;
    int EN = E + N;
    if (e >= EN) return;
    int s, d;
    if (e < E) {
        s = src_idx[e];
        d = dst_idx[e];
    } else {
        s = d = e - E;
    }
    int pos = atomicAdd(&cursor[d], 1);
    csr_src[pos] = s;
}

// ---------------- W1 convert + transpose: W1t[c][k] bf16 ----------------

__global__ __launch_bounds__(256) void prep_w1t(const float* __restrict__ W1,
                                                unsigned short* __restrict__ W1t) {
    __shared__ float tile[32][33];
    int bx = blockIdx.x & 7;   // col tile
    int by = blockIdx.x >> 3;  // k tile
    int tx = threadIdx.x & 31;
    int ty = threadIdx.x >> 5;  // 0..7
#pragma unroll
    for (int i = 0; i < 4; i++) {
        int k = by * 32 + ty + i * 8;
        tile[ty + i * 8][tx] = W1[k * 256 + bx * 32 + tx];
    }
    __syncthreads();
#pragma unroll
    for (int i = 0; i < 4; i++) {
        int c = bx * 32 + ty + i * 8;
        W1t[(size_t)c * 256 + by * 32 + tx] = f2bf(tile[tx][ty + i * 8]);
    }
}

// ---------------- Layer 1 GEMM via MFMA: h1 = bf16(x) @ bf16(W1), + logits ----------------
// Block = 256 thr = 4 waves, no LDS, no barriers. Wave w: rows m0+w*16..+15, all 256 cols.
// mfma_f32_16x16x32_bf16: A lane(row=l&15, k=(l>>4)*8+j); B lane(col=l&15, k=(l>>4)*8+j);
// C/D lane: col=l&15, row=(l>>4)*4+reg (verified layout, learn_hip m89).

__global__ __launch_bounds__(256) void gemm1_kernel(
    const float* __restrict__ x, const unsigned short* __restrict__ W1t,
    const float* __restrict__ a_src1, const float* __restrict__ a_dst1,
    unsigned short* __restrict__ h1, float* __restrict__ al_src1,
    float* __restrict__ al_dst1, int N) {
    const int tid = threadIdx.x;
    const int w = tid >> 6, l = tid & 63;
    const int lc = l & 15, lg = l >> 4;

    const int arow = blockIdx.x * 64 + w * 16 + lc;
    const int arowc = (arow < N) ? arow : (N - 1);

    f32x4 acc[16];
#pragma unroll
    for (int j = 0; j < 16; j++) acc[j] = (f32x4){0.f, 0.f, 0.f, 0.f};

    const float* xp = x + (size_t)arowc * 256 + lg * 8;

    for (int k0 = 0; k0 < 256; k0 += 32) {
        float4 v0 = *reinterpret_cast<const float4*>(xp + k0);
        float4 v1 = *reinterpret_cast<const float4*>(xp + k0 + 4);
        short8 af;
        af[0] = (short)f2bf(v0.x);
        af[1] = (short)f2bf(v0.y);
        af[2] = (short)f2bf(v0.z);
        af[3] = (short)f2bf(v0.w);
        af[4] = (short)f2bf(v1.x);
        af[5] = (short)f2bf(v1.y);
        af[6] = (short)f2bf(v1.z);
        af[7] = (short)f2bf(v1.w);
        const unsigned short* wp = W1t + (size_t)lc * 256 + k0 + lg * 8;
#pragma unroll
        for (int j = 0; j < 16; j++) {
            short8 bf = *reinterpret_cast<const short8*>(wp + (size_t)j * 16 * 256);
            acc[j] = __builtin_amdgcn_mfma_f32_16x16x32_bf16(af, bf, acc[j], 0, 0, 0);
        }
    }

    // epilogue: h1 store (bf16) + attention logits
    const int rbase = blockIdx.x * 64 + w * 16 + lg * 4;

#pragma unroll
    for (int j = 0; j < 16; j++) {
#pragma unroll
        for (int r = 0; r < 4; r++) {
            int rr = rbase + r;
            if (rr < N) h1[(size_t)rr * 256 + j * 16 + lc] = f2bf(acc[j][r]);
        }
    }

    float as_[16], ad_[16];
#pragma unroll
    for (int j = 0; j < 16; j++) {
        as_[j] = a_src1[j * 16 + lc];
        ad_[j] = a_dst1[j * 16 + lc];
    }
#pragma unroll
    for (int r = 0; r < 4; r++) {
        float s0 = 0.f, d0 = 0.f, s1 = 0.f, d1 = 0.f;
#pragma unroll
        for (int j = 0; j < 8; j++) {
            s0 += acc[j][r] * as_[j];
            d0 += acc[j][r] * ad_[j];
        }
#pragma unroll
        for (int j = 8; j < 16; j++) {
            s1 += acc[j][r] * as_[j];
            d1 += acc[j][r] * ad_[j];
        }
#pragma unroll
        for (int mask = 8; mask >= 1; mask >>= 1) {
            s0 += __shfl_xor(s0, mask, 64);
            s1 += __shfl_xor(s1, mask, 64);
            d0 += __shfl_xor(d0, mask, 64);
            d1 += __shfl_xor(d1, mask, 64);
        }
        int rr = rbase + r;
        if (lc == 0 && rr < N) {
            al_src1[rr * 2 + 0] = s0;
            al_src1[rr * 2 + 1] = s1;
            al_dst1[rr * 2 + 0] = d0;
            al_dst1[rr * 2 + 1] = d1;
        }
    }
}

// ---------------- Layer 1 aggregation (online softmax, 2-way unrolled) + fused L2 projection ----

__global__ __launch_bounds__(256) void agg1_kernel(
    const unsigned short* __restrict__ h1,
    const float* __restrict__ al_src1, const float* __restrict__ al_dst1,
    const int* __restrict__ offsets, const int* __restrict__ csr_src,
    const float* __restrict__ b1, const float* __restrict__ W2,
    const float* __restrict__ a_src2, const float* __restrict__ a_dst2,
    float* __restrict__ g2out, float* __restrict__ al_src2o,
    float* __restrict__ al_dst2o, int N) {
    int wid = (blockIdx.x * blockDim.x + threadIdx.x) >> 6;
    if (wid >= N) return;
    int lane = threadIdx.x & 63;
    int head = lane >> 5;
    int ch = lane * 4;

    int beg = offsets[wid], end = offsets[wid + 1];
    float aldv = al_dst1[wid * 2 + head];

    // two independent online-softmax states
    float mA = -INFINITY, lA = 0.f, pA0 = 0.f, pA1 = 0.f, pA2 = 0.f, pA3 = 0.f;
    float mB = -INFINITY, lB = 0.f, pB0 = 0.f, pB1 = 0.f, pB2 = 0.f, pB3 = 0.f;

    int e = beg;
    for (; e + 1 < end; e += 2) {
        int sA = csr_src[e];
        int sB = csr_src[e + 1];
        float lgA = al_src1[sA * 2 + head] + aldv;
        float lgB = al_src1[sB * 2 + head] + aldv;
        ushort4 hA = *reinterpret_cast<const ushort4*>(h1 + (size_t)sA * 256 + ch);
        ushort4 hB = *reinterpret_cast<const ushort4*>(h1 + (size_t)sB * 256 + ch);
        lgA = (lgA > 0.f) ? lgA : NEG_SLOPE * lgA;
        lgB = (lgB > 0.f) ? lgB : NEG_SLOPE * lgB;
        float mnA = fmaxf(mA, lgA);
        float scA = __expf(mA - mnA);
        float eA = __expf(lgA - mnA);
        pA0 = pA0 * scA + eA * bf2f(hA.x);
        pA1 = pA1 * scA + eA * bf2f(hA.y);
        pA2 = pA2 * scA + eA * bf2f(hA.z);
        pA3 = pA3 * scA + eA * bf2f(hA.w);
        lA = lA * scA + eA;
        mA = mnA;
        float mnB = fmaxf(mB, lgB);
        float scB = __expf(mB - mnB);
        float eB = __expf(lgB - mnB);
        pB0 = pB0 * scB + eB * bf2f(hB.x);
        pB1 = pB1 * scB + eB * bf2f(hB.y);
        pB2 = pB2 * scB + eB * bf2f(hB.z);
        pB3 = pB3 * scB + eB * bf2f(hB.w);
        lB = lB * scB + eB;
        mB = mnB;
    }
    if (e < end) {
        int sA = csr_src[e];
        float lgA = al_src1[sA * 2 + head] + aldv;
        ushort4 hA = *reinterpret_cast<const ushort4*>(h1 + (size_t)sA * 256 + ch);
        lgA = (lgA > 0.f) ? lgA : NEG_SLOPE * lgA;
        float mnA = fmaxf(mA, lgA);
        float scA = __expf(mA - mnA);
        float eA = __expf(lgA - mnA);
        pA0 = pA0 * scA + eA * bf2f(hA.x);
        pA1 = pA1 * scA + eA * bf2f(hA.y);
        pA2 = pA2 * scA + eA * bf2f(hA.z);
        pA3 = pA3 * scA + eA * bf2f(hA.w);
        lA = lA * scA + eA;
        mA = mnA;
    }
    // merge B into A (every node has a self-loop, so state A is non-empty)
    float mn = fmaxf(mA, mB);
    float scA = __expf(mA - mn);
    float scB = (lB > 0.f) ? __expf(mB - mn) : 0.f;
    float a0 = pA0 * scA + pB0 * scB;
    float a1 = pA1 * scA + pB1 * scB;
    float a2 = pA2 * scA + pB2 * scB;
    float a3 = pA3 * scA + pB3 * scB;
    float lsum = lA * scA + lB * scB;

    float inv = 1.f / lsum;
    float4 bb = *reinterpret_cast<const float4*>(b1 + ch);
    float r0 = fmaxf(a0 * inv + bb.x, 0.f);
    float r1 = fmaxf(a1 * inv + bb.y, 0.f);
    float r2 = fmaxf(a2 * inv + bb.z, 0.f);
    float r3 = fmaxf(a3 * inv + bb.w, 0.f);

    float4 w0 = *reinterpret_cast<const float4*>(W2 + (size_t)(ch + 0) * 4);
    float4 w1 = *reinterpret_cast<const float4*>(W2 + (size_t)(ch + 1) * 4);
    float4 w2 = *reinterpret_cast<const float4*>(W2 + (size_t)(ch + 2) * 4);
    float4 w3 = *reinterpret_cast<const float4*>(W2 + (size_t)(ch + 3) * 4);
    float g0 = r0 * w0.x + r1 * w1.x + r2 * w2.x + r3 * w3.x;
    float g1 = r0 * w0.y + r1 * w1.y + r2 * w2.y + r3 * w3.y;
    float g2v = r0 * w0.z + r1 * w1.z + r2 * w2.z + r3 * w3.z;
    float g3 = r0 * w0.w + r1 * w1.w + r2 * w2.w + r3 * w3.w;
#pragma unroll
    for (int mask = 32; mask >= 1; mask >>= 1) {
        g0 += __shfl_xor(g0, mask, 64);
        g1 += __shfl_xor(g1, mask, 64);
        g2v += __shfl_xor(g2v, mask, 64);
        g3 += __shfl_xor(g3, mask, 64);
    }
    if (lane == 0) {
        float4 gv;
        gv.x = g0; gv.y = g1; gv.z = g2v; gv.w = g3;
        *reinterpret_cast<float4*>(g2out + (size_t)wid * 4) = gv;
        al_src2o[wid] = g0 * a_src2[0] + g1 * a_src2[1] + g2v * a_src2[2] + g3 * a_src2[3];
        al_dst2o[wid] = g0 * a_dst2[0] + g1 * a_dst2[1] + g2v * a_dst2[2] + g3 * a_dst2[3];
    }
}

// ---------------- Layer 2 aggregation (2-way unrolled) + bias + log_softmax ----------------

__global__ __launch_bounds__(256) void agg2_kernel(
    const float* __restrict__ g2, const float* __restrict__ al_src2,
    const float* __restrict__ al_dst2, const int* __restrict__ offsets,
    const int* __restrict__ csr_src, const float* __restrict__ b2,
    float* __restrict__ out, int N) {
    int wid = (blockIdx.x * blockDim.x + threadIdx.x) >> 6;
    if (wid >= N) return;
    int lane = threadIdx.x & 63;

    int beg = offsets[wid], end = offsets[wid + 1];
    float aldv = al_dst2[wid];

    float mA = -INFINITY, lA = 0.f, pA0 = 0.f, pA1 = 0.f, pA2 = 0.f, pA3 = 0.f;
    float mB = -INFINITY, lB = 0.f, pB0 = 0.f, pB1 = 0.f, pB2 = 0.f, pB3 = 0.f;

    int e = beg;
    for (; e + 1 < end; e += 2) {
        int sA = csr_src[e];
        int sB = csr_src[e + 1];
        float lgA = al_src2[sA] + aldv;
        float lgB = al_src2[sB] + aldv;
        float4 gA = *reinterpret_cast<const float4*>(g2 + (size_t)sA * 4);
        float4 gB = *reinterpret_cast<const float4*>(g2 + (size_t)sB * 4);
        lgA = (lgA > 0.f) ? lgA : NEG_SLOPE * lgA;
        lgB = (lgB > 0.f) ? lgB : NEG_SLOPE * lgB;
        float mnA = fmaxf(mA, lgA);
        float scA = __expf(mA - mnA);
        float eA = __expf(lgA - mnA);
        pA0 = pA0 * scA + eA * gA.x;
        pA1 = pA1 * scA + eA * gA.y;
        pA2 = pA2 * scA + eA * gA.z;
        pA3 = pA3 * scA + eA * gA.w;
        lA = lA * scA + eA;
        mA = mnA;
        float mnB = fmaxf(mB, lgB);
        float scB = __expf(mB - mnB);
        float eB = __expf(lgB - mnB);
        pB0 = pB0 * scB + eB * gB.x;
        pB1 = pB1 * scB + eB * gB.y;
        pB2 = pB2 * scB + eB * gB.z;
        pB3 = pB3 * scB + eB * gB.w;
        lB = lB * scB + eB;
        mB = mnB;
    }
    if (e < end) {
        int sA = csr_src[e];
        float lgA = al_src2[sA] + aldv;
        float4 gA = *reinterpret_cast<const float4*>(g2 + (size_t)sA * 4);
        lgA = (lgA > 0.f) ? lgA : NEG_SLOPE * lgA;
        float mnA = fmaxf(mA, lgA);
        float scA = __expf(mA - mnA);
        float eA = __expf(lgA - mnA);
        pA0 = pA0 * scA + eA * gA.x;
        pA1 = pA1 * scA + eA * gA.y;
        pA2 = pA2 * scA + eA * gA.z;
        pA3 = pA3 * scA + eA * gA.w;
        lA = lA * scA + eA;
        mA = mnA;
    }
    float mn = fmaxf(mA, mB);
    float scA = __expf(mA - mn);
    float scB = (lB > 0.f) ? __expf(mB - mn) : 0.f;
    float a0 = pA0 * scA + pB0 * scB;
    float a1 = pA1 * scA + pB1 * scB;
    float a2 = pA2 * scA + pB2 * scB;
    float a3 = pA3 * scA + pB3 * scB;
    float lsum = lA * scA + lB * scB;

    float inv = 1.f / lsum;
    float r0 = a0 * inv + b2[0];
    float r1 = a1 * inv + b2[1];
    float r2 = a2 * inv + b2[2];
    float r3 = a3 * inv + b2[3];
    float mx = fmaxf(fmaxf(r0, r1), fmaxf(r2, r3));
    float s0 = __expf(r0 - mx), s1 = __expf(r1 - mx), s2 = __expf(r2 - mx), s3 = __expf(r3 - mx);
    float ls = __logf(s0 + s1 + s2 + s3);
    if (lane == 0) {
        float4 ov;
        ov.x = r0 - mx - ls;
        ov.y = r1 - mx - ls;
        ov.z = r2 - mx - ls;
        ov.w = r3 - mx - ls;
        *reinterpret_cast<float4*>(out + (size_t)wid * 4) = ov;
    }
}

// ---------------- host ----------------

extern "C" void kernel_launch(void* const* d_in, const int* in_sizes, int n_in,
                              void* d_out, int out_size, void* d_ws, size_t ws_size,
                              hipStream_t stream) {
    const float* x = (const float*)d_in[0];
    const int* edge_index = (const int*)d_in[1];
    const float* W1 = (const float*)d_in[2];
    const float* a_src1 = (const float*)d_in[3];
    const float* a_dst1 = (const float*)d_in[4];
    const float* b1 = (const float*)d_in[5];
    const float* W2 = (const float*)d_in[6];
    const float* a_src2 = (const float*)d_in[7];
    const float* a_dst2 = (const float*)d_in[8];
    const float* b2 = (const float*)d_in[9];
    float* out = (float*)d_out;

    const int N = in_sizes[0] / 256;
    const int E = in_sizes[1] / 2;
    const int EN = E + N;
    const int* src_idx = edge_index;
    const int* dst_idx = edge_index + E;

    char* ws = (char*)d_ws;
    size_t off = 0;
    auto alloc = [&](size_t bytes) -> char* {
        char* p = ws + off;
        off += (bytes + 255) & ~(size_t)255;
        return p;
    };
    unsigned short* h1 = (unsigned short*)alloc((size_t)N * 256 * 2);
    unsigned short* W1t = (unsigned short*)alloc((size_t)256 * 256 * 2);
    float* al_src1 = (float*)alloc((size_t)N * 2 * 4);
    float* al_dst1 = (float*)alloc((size_t)N * 2 * 4);
    float* g2 = (float*)alloc((size_t)N * 4 * 4);
    float* al_src2 = (float*)alloc((size_t)N * 4);
    float* al_dst2 = (float*)alloc((size_t)N * 4);
    int* offsets = (int*)alloc((size_t)(N + 1) * 4);
    int* cursor = (int*)alloc((size_t)N * 4);
    int* csr_src = (int*)alloc((size_t)EN * 4);
    int* blockSums = (int*)alloc(128 * 4);

    hipMemsetAsync(cursor, 0, (size_t)N * 4, stream);

    prep_w1t<<<64, 256, 0, stream>>>(W1, W1t);

    int hb = (EN + 255) / 256;
    hist_kernel<<<hb, 256, 0, stream>>>(dst_idx, cursor, E, N);

    int nb = (N + SCAN_ELEMS - 1) / SCAN_ELEMS;
    scan_blocks_kernel<<<nb, SCAN_TPB, 0, stream>>>(cursor, offsets, blockSums, N);
    scan_sums_kernel<<<1, 128, 0, stream>>>(blockSums, nb);
    scan_finalize_kernel<<<nb, SCAN_TPB, 0, stream>>>(offsets, blockSums, cursor, N, EN);

    scatter_kernel<<<hb, 256, 0, stream>>>(src_idx, dst_idx, cursor, csr_src, E, N);

    int gb = (N + 63) / 64;
    gemm1_kernel<<<gb, 256, 0, stream>>>(x, W1t, a_src1, a_dst1, h1, al_src1, al_dst1, N);

    int ab = (N + 3) / 4;
    agg1_kernel<<<ab, 256, 0, stream>>>(h1, al_src1, al_dst1, offsets, csr_src, b1, W2,
                                        a_src2, a_dst2, g2, al_src2, al_dst2, N);
    agg2_kernel<<<ab, 256, 0, stream>>>(g2, al_src2, al_dst2, offsets, csr_src, b2, out, N);
}

// Round 7
// 682.902 us; speedup vs baseline: 1.2912x; 1.0318x over previous
//
#include <hip/hip_runtime.h>
#include <hip/hip_bf16.h>

#define NEG_SLOPE 0.2f
#define SCAN_TPB 256
#define SCAN_VPT 4
#define SCAN_ELEMS (SCAN_TPB * SCAN_VPT)

typedef __attribute__((ext_vector_type(8))) short short8;
typedef __attribute__((ext_vector_type(4))) float f32x4;

static __device__ __forceinline__ unsigned short f2bf(float v) {
    __hip_bfloat16 b = __float2bfloat16(v);
    return *reinterpret_cast<unsigned short*>(&b);
}
static __device__ __forceinline__ float bf2f(unsigned short u) {
    unsigned int x = ((unsigned int)u) << 16;
    return __uint_as_float(x);
}
static __device__ __forceinline__ float lrelu(float v) {
    return (v > 0.f) ? v : NEG_SLOPE * v;
}

// ---------------- CSR build ----------------

__global__ void hist_kernel(const int* __restrict__ dst_idx, int* __restrict__ count,
                            int E, int N) {
    int e = blockIdx.x * blockDim.x + threadIdx.x;
    int EN = E + N;
    if (e >= EN) return;
    int d = (e < E) ? dst_idx[e] : (e - E);
    atomicAdd(&count[d], 1);
}

__global__ void scan_blocks_kernel(const int* __restrict__ count, int* __restrict__ local_ex,
                                   int* __restrict__ blockSums, int n) {
    __shared__ int sm[SCAN_TPB];
    int tid = threadIdx.x;
    int base = blockIdx.x * SCAN_ELEMS + tid * SCAN_VPT;
    int v[SCAN_VPT];
    int s = 0;
#pragma unroll
    for (int i = 0; i < SCAN_VPT; i++) {
        v[i] = (base + i < n) ? count[base + i] : 0;
        s += v[i];
    }
    sm[tid] = s;
    __syncthreads();
#pragma unroll
    for (int off = 1; off < SCAN_TPB; off <<= 1) {
        int t = (tid >= off) ? sm[tid - off] : 0;
        __syncthreads();
        sm[tid] += t;
        __syncthreads();
    }
    int ex = sm[tid] - s;
#pragma unroll
    for (int i = 0; i < SCAN_VPT; i++) {
        if (base + i < n) local_ex[base + i] = ex;
        ex += v[i];
    }
    if (tid == SCAN_TPB - 1) blockSums[blockIdx.x] = sm[tid];
}

__global__ void scan_sums_kernel(int* __restrict__ blockSums, int nb) {
    __shared__ int sm[128];
    int tid = threadIdx.x;
    int v = (tid < nb) ? blockSums[tid] : 0;
    sm[tid] = v;
    __syncthreads();
    for (int off = 1; off < 128; off <<= 1) {
        int t = (tid >= off) ? sm[tid - off] : 0;
        __syncthreads();
        sm[tid] += t;
        __syncthreads();
    }
    if (tid < nb) blockSums[tid] = sm[tid] - v;
}

__global__ void scan_finalize_kernel(int* __restrict__ offsets, const int* __restrict__ blockSums,
                                     int* __restrict__ cursor, int n, int total) {
    int tid = threadIdx.x;
    int base = blockIdx.x * SCAN_ELEMS + tid * SCAN_VPT;
    int add = blockSums[blockIdx.x];
#pragma unroll
    for (int i = 0; i < SCAN_VPT; i++) {
        int idx = base + i;
        if (idx < n) {
            int val = offsets[idx] + add;
            offsets[idx] = val;
            cursor[idx] = val;
        }
    }
    if (blockIdx.x == 0 && tid == 0) offsets[n] = total;
}

__global__ void scatter_kernel(const int* __restrict__ src_idx, const int* __restrict__ dst_idx,
                               int* __restrict__ cursor, int* __restrict__ csr_src,
                               int E, int N) {
    int e = blockIdx.x * blockDim.x + threadIdx.x;
    int EN = E + N;
    if (e >= EN) return;
    int s, d;
    if (e < E) {
        s = src_idx[e];
        d = dst_idx[e];
    } else {
        s = d = e - E;
    }
    int pos = atomicAdd(&cursor[d], 1);
    csr_src[pos] = s;
}

// ---------------- W1 convert + transpose: W1t[c][k] bf16 ----------------

__global__ __launch_bounds__(256) void prep_w1t(const float* __restrict__ W1,
                                                unsigned short* __restrict__ W1t) {
    __shared__ float tile[32][33];
    int bx = blockIdx.x & 7;   // col tile
    int by = blockIdx.x >> 3;  // k tile
    int tx = threadIdx.x & 31;
    int ty = threadIdx.x >> 5;  // 0..7
#pragma unroll
    for (int i = 0; i < 4; i++) {
        int k = by * 32 + ty + i * 8;
        tile[ty + i * 8][tx] = W1[k * 256 + bx * 32 + tx];
    }
    __syncthreads();
#pragma unroll
    for (int i = 0; i < 4; i++) {
        int c = bx * 32 + ty + i * 8;
        W1t[(size_t)c * 256 + by * 32 + tx] = f2bf(tile[tx][ty + i * 8]);
    }
}

// ---------------- Layer 1 GEMM via MFMA: h1 = bf16(x) @ bf16(W1), + logits ----------------
// Block = 256 thr = 4 waves, no LDS, no barriers. Wave w: rows m0+w*16..+15, all 256 cols.
// mfma_f32_16x16x32_bf16: C/D lane mapping col=l&15, row=(l>>4)*4+reg (learn_hip m89).

__global__ __launch_bounds__(256) void gemm1_kernel(
    const float* __restrict__ x, const unsigned short* __restrict__ W1t,
    const float* __restrict__ a_src1, const float* __restrict__ a_dst1,
    unsigned short* __restrict__ h1, float* __restrict__ al_src1,
    float* __restrict__ al_dst1, int N) {
    const int tid = threadIdx.x;
    const int w = tid >> 6, l = tid & 63;
    const int lc = l & 15, lg = l >> 4;

    const int arow = blockIdx.x * 64 + w * 16 + lc;
    const int arowc = (arow < N) ? arow : (N - 1);

    f32x4 acc[16];
#pragma unroll
    for (int j = 0; j < 16; j++) acc[j] = (f32x4){0.f, 0.f, 0.f, 0.f};

    const float* xp = x + (size_t)arowc * 256 + lg * 8;

    for (int k0 = 0; k0 < 256; k0 += 32) {
        float4 v0 = *reinterpret_cast<const float4*>(xp + k0);
        float4 v1 = *reinterpret_cast<const float4*>(xp + k0 + 4);
        short8 af;
        af[0] = (short)f2bf(v0.x);
        af[1] = (short)f2bf(v0.y);
        af[2] = (short)f2bf(v0.z);
        af[3] = (short)f2bf(v0.w);
        af[4] = (short)f2bf(v1.x);
        af[5] = (short)f2bf(v1.y);
        af[6] = (short)f2bf(v1.z);
        af[7] = (short)f2bf(v1.w);
        const unsigned short* wp = W1t + (size_t)lc * 256 + k0 + lg * 8;
#pragma unroll
        for (int j = 0; j < 16; j++) {
            short8 bf = *reinterpret_cast<const short8*>(wp + (size_t)j * 16 * 256);
            acc[j] = __builtin_amdgcn_mfma_f32_16x16x32_bf16(af, bf, acc[j], 0, 0, 0);
        }
    }

    // epilogue: h1 store (bf16) + attention logits
    const int rbase = blockIdx.x * 64 + w * 16 + lg * 4;

#pragma unroll
    for (int j = 0; j < 16; j++) {
#pragma unroll
        for (int r = 0; r < 4; r++) {
            int rr = rbase + r;
            if (rr < N) h1[(size_t)rr * 256 + j * 16 + lc] = f2bf(acc[j][r]);
        }
    }

    float as_[16], ad_[16];
#pragma unroll
    for (int j = 0; j < 16; j++) {
        as_[j] = a_src1[j * 16 + lc];
        ad_[j] = a_dst1[j * 16 + lc];
    }
#pragma unroll
    for (int r = 0; r < 4; r++) {
        float s0 = 0.f, d0 = 0.f, s1 = 0.f, d1 = 0.f;
#pragma unroll
        for (int j = 0; j < 8; j++) {
            s0 += acc[j][r] * as_[j];
            d0 += acc[j][r] * ad_[j];
        }
#pragma unroll
        for (int j = 8; j < 16; j++) {
            s1 += acc[j][r] * as_[j];
            d1 += acc[j][r] * ad_[j];
        }
#pragma unroll
        for (int mask = 8; mask >= 1; mask >>= 1) {
            s0 += __shfl_xor(s0, mask, 64);
            s1 += __shfl_xor(s1, mask, 64);
            d0 += __shfl_xor(d0, mask, 64);
            d1 += __shfl_xor(d1, mask, 64);
        }
        int rr = rbase + r;
        if (lc == 0 && rr < N) {
            al_src1[rr * 2 + 0] = s0;
            al_src1[rr * 2 + 1] = s1;
            al_dst1[rr * 2 + 0] = d0;
            al_dst1[rr * 2 + 1] = d1;
        }
    }
}

// ---------------- Layer 1 aggregation (direct exp softmax, 4-edge batched) + fused L2 proj ----
// Logits provably tiny (std ~0.33): exp(e)/sum(exp(e)) == exp(e-m)/sum(exp(e-m)), no overflow
// risk below |e|~85. Dropping the online max removes 2 exp + 5-mul rescale + fmax per edge.

__global__ __launch_bounds__(256) void agg1_kernel(
    const unsigned short* __restrict__ h1,
    const float* __restrict__ al_src1, const float* __restrict__ al_dst1,
    const int* __restrict__ offsets, const int* __restrict__ csr_src,
    const float* __restrict__ b1, const float* __restrict__ W2,
    const float* __restrict__ a_src2, const float* __restrict__ a_dst2,
    float* __restrict__ g2out, float* __restrict__ al_src2o,
    float* __restrict__ al_dst2o, int N) {
    int wid = (blockIdx.x * blockDim.x + threadIdx.x) >> 6;
    if (wid >= N) return;
    int lane = threadIdx.x & 63;
    int head = lane >> 5;
    int ch = lane * 4;

    int beg = offsets[wid], end = offsets[wid + 1];
    float aldv = al_dst1[wid * 2 + head];

    float l = 0.f, p0 = 0.f, p1 = 0.f, p2 = 0.f, p3 = 0.f;

    int e = beg;
    for (; e + 3 < end; e += 4) {
        int sa = csr_src[e];
        int sb = csr_src[e + 1];
        int sc = csr_src[e + 2];
        int sd = csr_src[e + 3];
        float la = al_src1[sa * 2 + head] + aldv;
        float lb = al_src1[sb * 2 + head] + aldv;
        float lcv = al_src1[sc * 2 + head] + aldv;
        float ld = al_src1[sd * 2 + head] + aldv;
        ushort4 ha = *reinterpret_cast<const ushort4*>(h1 + (size_t)sa * 256 + ch);
        ushort4 hb = *reinterpret_cast<const ushort4*>(h1 + (size_t)sb * 256 + ch);
        ushort4 hc = *reinterpret_cast<const ushort4*>(h1 + (size_t)sc * 256 + ch);
        ushort4 hd = *reinterpret_cast<const ushort4*>(h1 + (size_t)sd * 256 + ch);
        float wa = __expf(lrelu(la));
        float wb = __expf(lrelu(lb));
        float wc = __expf(lrelu(lcv));
        float wd = __expf(lrelu(ld));
        p0 += wa * bf2f(ha.x) + wb * bf2f(hb.x) + wc * bf2f(hc.x) + wd * bf2f(hd.x);
        p1 += wa * bf2f(ha.y) + wb * bf2f(hb.y) + wc * bf2f(hc.y) + wd * bf2f(hd.y);
        p2 += wa * bf2f(ha.z) + wb * bf2f(hb.z) + wc * bf2f(hc.z) + wd * bf2f(hd.z);
        p3 += wa * bf2f(ha.w) + wb * bf2f(hb.w) + wc * bf2f(hc.w) + wd * bf2f(hd.w);
        l += (wa + wb) + (wc + wd);
    }
    for (; e < end; ++e) {
        int sa = csr_src[e];
        float la = al_src1[sa * 2 + head] + aldv;
        ushort4 ha = *reinterpret_cast<const ushort4*>(h1 + (size_t)sa * 256 + ch);
        float wa = __expf(lrelu(la));
        p0 += wa * bf2f(ha.x);
        p1 += wa * bf2f(ha.y);
        p2 += wa * bf2f(ha.z);
        p3 += wa * bf2f(ha.w);
        l += wa;
    }

    float inv = 1.f / l;
    float4 bb = *reinterpret_cast<const float4*>(b1 + ch);
    float r0 = fmaxf(p0 * inv + bb.x, 0.f);
    float r1 = fmaxf(p1 * inv + bb.y, 0.f);
    float r2 = fmaxf(p2 * inv + bb.z, 0.f);
    float r3 = fmaxf(p3 * inv + bb.w, 0.f);

    // fused layer-2 projection: g[c] = sum_k h2[k] * W2[k][c], k distributed over wave
    float4 w0 = *reinterpret_cast<const float4*>(W2 + (size_t)(ch + 0) * 4);
    float4 w1 = *reinterpret_cast<const float4*>(W2 + (size_t)(ch + 1) * 4);
    float4 w2 = *reinterpret_cast<const float4*>(W2 + (size_t)(ch + 2) * 4);
    float4 w3 = *reinterpret_cast<const float4*>(W2 + (size_t)(ch + 3) * 4);
    float g0 = r0 * w0.x + r1 * w1.x + r2 * w2.x + r3 * w3.x;
    float g1 = r0 * w0.y + r1 * w1.y + r2 * w2.y + r3 * w3.y;
    float g2v = r0 * w0.z + r1 * w1.z + r2 * w2.z + r3 * w3.z;
    float g3 = r0 * w0.w + r1 * w1.w + r2 * w2.w + r3 * w3.w;
#pragma unroll
    for (int mask = 32; mask >= 1; mask >>= 1) {
        g0 += __shfl_xor(g0, mask, 64);
        g1 += __shfl_xor(g1, mask, 64);
        g2v += __shfl_xor(g2v, mask, 64);
        g3 += __shfl_xor(g3, mask, 64);
    }
    if (lane == 0) {
        float4 gv;
        gv.x = g0; gv.y = g1; gv.z = g2v; gv.w = g3;
        *reinterpret_cast<float4*>(g2out + (size_t)wid * 4) = gv;
        al_src2o[wid] = g0 * a_src2[0] + g1 * a_src2[1] + g2v * a_src2[2] + g3 * a_src2[3];
        al_dst2o[wid] = g0 * a_dst2[0] + g1 * a_dst2[1] + g2v * a_dst2[2] + g3 * a_dst2[3];
    }
}

// ---------------- Layer 2 aggregation (direct exp, 4-edge batched) + bias + log_softmax ------

__global__ __launch_bounds__(256) void agg2_kernel(
    const float* __restrict__ g2, const float* __restrict__ al_src2,
    const float* __restrict__ al_dst2, const int* __restrict__ offsets,
    const int* __restrict__ csr_src, const float* __restrict__ b2,
    float* __restrict__ out, int N) {
    int wid = (blockIdx.x * blockDim.x + threadIdx.x) >> 6;
    if (wid >= N) return;
    int lane = threadIdx.x & 63;

    int beg = offsets[wid], end = offsets[wid + 1];
    float aldv = al_dst2[wid];

    float l = 0.f, p0 = 0.f, p1 = 0.f, p2 = 0.f, p3 = 0.f;

    int e = beg;
    for (; e + 3 < end; e += 4) {
        int sa = csr_src[e];
        int sb = csr_src[e + 1];
        int sc = csr_src[e + 2];
        int sd = csr_src[e + 3];
        float la = al_src2[sa] + aldv;
        float lb = al_src2[sb] + aldv;
        float lcv = al_src2[sc] + aldv;
        float ld = al_src2[sd] + aldv;
        float4 ga = *reinterpret_cast<const float4*>(g2 + (size_t)sa * 4);
        float4 gb = *reinterpret_cast<const float4*>(g2 + (size_t)sb * 4);
        float4 gc = *reinterpret_cast<const float4*>(g2 + (size_t)sc * 4);
        float4 gd = *reinterpret_cast<const float4*>(g2 + (size_t)sd * 4);
        float wa = __expf(lrelu(la));
        float wb = __expf(lrelu(lb));
        float wc = __expf(lrelu(lcv));
        float wd = __expf(lrelu(ld));
        p0 += wa * ga.x + wb * gb.x + wc * gc.x + wd * gd.x;
        p1 += wa * ga.y + wb * gb.y + wc * gc.y + wd * gd.y;
        p2 += wa * ga.z + wb * gb.z + wc * gc.z + wd * gd.z;
        p3 += wa * ga.w + wb * gb.w + wc * gc.w + wd * gd.w;
        l += (wa + wb) + (wc + wd);
    }
    for (; e < end; ++e) {
        int sa = csr_src[e];
        float la = al_src2[sa] + aldv;
        float4 ga = *reinterpret_cast<const float4*>(g2 + (size_t)sa * 4);
        float wa = __expf(lrelu(la));
        p0 += wa * ga.x;
        p1 += wa * ga.y;
        p2 += wa * ga.z;
        p3 += wa * ga.w;
        l += wa;
    }

    float inv = 1.f / l;
    float r0 = p0 * inv + b2[0];
    float r1 = p1 * inv + b2[1];
    float r2 = p2 * inv + b2[2];
    float r3 = p3 * inv + b2[3];
    float mx = fmaxf(fmaxf(r0, r1), fmaxf(r2, r3));
    float s0 = __expf(r0 - mx), s1 = __expf(r1 - mx), s2 = __expf(r2 - mx), s3 = __expf(r3 - mx);
    float ls = __logf(s0 + s1 + s2 + s3);
    if (lane == 0) {
        float4 ov;
        ov.x = r0 - mx - ls;
        ov.y = r1 - mx - ls;
        ov.z = r2 - mx - ls;
        ov.w = r3 - mx - ls;
        *reinterpret_cast<float4*>(out + (size_t)wid * 4) = ov;
    }
}

// ---------------- host ----------------

extern "C" void kernel_launch(void* const* d_in, const int* in_sizes, int n_in,
                              void* d_out, int out_size, void* d_ws, size_t ws_size,
                              hipStream_t stream) {
    const float* x = (const float*)d_in[0];
    const int* edge_index = (const int*)d_in[1];
    const float* W1 = (const float*)d_in[2];
    const float* a_src1 = (const float*)d_in[3];
    const float* a_dst1 = (const float*)d_in[4];
    const float* b1 = (const float*)d_in[5];
    const float* W2 = (const float*)d_in[6];
    const float* a_src2 = (const float*)d_in[7];
    const float* a_dst2 = (const float*)d_in[8];
    const float* b2 = (const float*)d_in[9];
    float* out = (float*)d_out;

    const int N = in_sizes[0] / 256;
    const int E = in_sizes[1] / 2;
    const int EN = E + N;
    const int* src_idx = edge_index;
    const int* dst_idx = edge_index + E;

    char* ws = (char*)d_ws;
    size_t off = 0;
    auto alloc = [&](size_t bytes) -> char* {
        char* p = ws + off;
        off += (bytes + 255) & ~(size_t)255;
        return p;
    };
    unsigned short* h1 = (unsigned short*)alloc((size_t)N * 256 * 2);
    unsigned short* W1t = (unsigned short*)alloc((size_t)256 * 256 * 2);
    float* al_src1 = (float*)alloc((size_t)N * 2 * 4);
    float* al_dst1 = (float*)alloc((size_t)N * 2 * 4);
    float* g2 = (float*)alloc((size_t)N * 4 * 4);
    float* al_src2 = (float*)alloc((size_t)N * 4);
    float* al_dst2 = (float*)alloc((size_t)N * 4);
    int* offsets = (int*)alloc((size_t)(N + 1) * 4);
    int* cursor = (int*)alloc((size_t)N * 4);
    int* csr_src = (int*)alloc((size_t)EN * 4);
    int* blockSums = (int*)alloc(128 * 4);

    hipMemsetAsync(cursor, 0, (size_t)N * 4, stream);

    prep_w1t<<<64, 256, 0, stream>>>(W1, W1t);

    int hb = (EN + 255) / 256;
    hist_kernel<<<hb, 256, 0, stream>>>(dst_idx, cursor, E, N);

    int nb = (N + SCAN_ELEMS - 1) / SCAN_ELEMS;
    scan_blocks_kernel<<<nb, SCAN_TPB, 0, stream>>>(cursor, offsets, blockSums, N);
    scan_sums_kernel<<<1, 128, 0, stream>>>(blockSums, nb);
    scan_finalize_kernel<<<nb, SCAN_TPB, 0, stream>>>(offsets, blockSums, cursor, N, EN);

    scatter_kernel<<<hb, 256, 0, stream>>>(src_idx, dst_idx, cursor, csr_src, E, N);

    int gb = (N + 63) / 64;
    gemm1_kernel<<<gb, 256, 0, stream>>>(x, W1t, a_src1, a_dst1, h1, al_src1, al_dst1, N);

    int ab = (N + 3) / 4;
    agg1_kernel<<<ab, 256, 0, stream>>>(h1, al_src1, al_dst1, offsets, csr_src, b1, W2,
                                        a_src2, a_dst2, g2, al_src2, al_dst2, N);
    agg2_kernel<<<ab, 256, 0, stream>>>(g2, al_src2, al_dst2, offsets, csr_src, b2, out, N);
}

// Round 8
// 663.413 us; speedup vs baseline: 1.3292x; 1.0294x over previous
//
#include <hip/hip_runtime.h>
#include <hip/hip_bf16.h>

#define NEG_SLOPE 0.2f
#define SCAN_TPB 256
#define SCAN_VPT 4
#define SCAN_ELEMS (SCAN_TPB * SCAN_VPT)

typedef __attribute__((ext_vector_type(8))) short short8;
typedef __attribute__((ext_vector_type(4))) float f32x4;

static __device__ __forceinline__ unsigned short f2bf(float v) {
    __hip_bfloat16 b = __float2bfloat16(v);
    return *reinterpret_cast<unsigned short*>(&b);
}
static __device__ __forceinline__ float bf2f(unsigned short u) {
    unsigned int x = ((unsigned int)u) << 16;
    return __uint_as_float(x);
}
static __device__ __forceinline__ float lrelu(float v) {
    return (v > 0.f) ? v : NEG_SLOPE * v;
}

// ---------------- CSR build ----------------

__global__ void hist_kernel(const int* __restrict__ dst_idx, int* __restrict__ count,
                            int E, int N) {
    int e = blockIdx.x * blockDim.x + threadIdx.x;
    int EN = E + N;
    if (e >= EN) return;
    int d = (e < E) ? dst_idx[e] : (e - E);
    atomicAdd(&count[d], 1);
}

__global__ void scan_blocks_kernel(const int* __restrict__ count, int* __restrict__ local_ex,
                                   int* __restrict__ blockSums, int n) {
    __shared__ int sm[SCAN_TPB];
    int tid = threadIdx.x;
    int base = blockIdx.x * SCAN_ELEMS + tid * SCAN_VPT;
    int v[SCAN_VPT];
    int s = 0;
#pragma unroll
    for (int i = 0; i < SCAN_VPT; i++) {
        v[i] = (base + i < n) ? count[base + i] : 0;
        s += v[i];
    }
    sm[tid] = s;
    __syncthreads();
#pragma unroll
    for (int off = 1; off < SCAN_TPB; off <<= 1) {
        int t = (tid >= off) ? sm[tid - off] : 0;
        __syncthreads();
        sm[tid] += t;
        __syncthreads();
    }
    int ex = sm[tid] - s;
#pragma unroll
    for (int i = 0; i < SCAN_VPT; i++) {
        if (base + i < n) local_ex[base + i] = ex;
        ex += v[i];
    }
    if (tid == SCAN_TPB - 1) blockSums[blockIdx.x] = sm[tid];
}

__global__ void scan_sums_kernel(int* __restrict__ blockSums, int nb) {
    __shared__ int sm[128];
    int tid = threadIdx.x;
    int v = (tid < nb) ? blockSums[tid] : 0;
    sm[tid] = v;
    __syncthreads();
    for (int off = 1; off < 128; off <<= 1) {
        int t = (tid >= off) ? sm[tid - off] : 0;
        __syncthreads();
        sm[tid] += t;
        __syncthreads();
    }
    if (tid < nb) blockSums[tid] = sm[tid] - v;
}

__global__ void scan_finalize_kernel(int* __restrict__ offsets, const int* __restrict__ blockSums,
                                     int* __restrict__ cursor, int n, int total) {
    int tid = threadIdx.x;
    int base = blockIdx.x * SCAN_ELEMS + tid * SCAN_VPT;
    int add = blockSums[blockIdx.x];
#pragma unroll
    for (int i = 0; i < SCAN_VPT; i++) {
        int idx = base + i;
        if (idx < n) {
            int val = offsets[idx] + add;
            offsets[idx] = val;
            cursor[idx] = val;
        }
    }
    if (blockIdx.x == 0 && tid == 0) offsets[n] = total;
}

__global__ void scatter_kernel(const int* __restrict__ src_idx, const int* __restrict__ dst_idx,
                               int* __restrict__ cursor, int* __restrict__ csr_src,
                               int E, int N) {
    int e = blockIdx.x * blockDim.x + threadIdx.x;
    int EN = E + N;
    if (e >= EN) return;
    int s, d;
    if (e < E) {
        s = src_idx[e];
        d = dst_idx[e];
    } else {
        s = d = e - E;
    }
    int pos = atomicAdd(&cursor[d], 1);
    csr_src[pos] = s;
}

// ---------------- W1 repack: W1s = 8 k-tiles, each the exact LDS image ----------------
// Tile t (k0 = t*32): [lg(4)][col(256)][kk(8)] bf16, 16 KB. Fragment for lane (lc,lg),
// output col j*16+lc: contiguous 8 shorts at lg*2048 + col*8.

__global__ __launch_bounds__(256) void prep_w1s(const float* __restrict__ W1,
                                                unsigned short* __restrict__ W1s) {
    int idx = blockIdx.x * 256 + threadIdx.x;  // 65536 total
    int col = idx & 255;
    int k = idx >> 8;  // 0..255
    int t = k >> 5, lg = (k >> 3) & 3, kk = k & 7;
    W1s[t * 8192 + lg * 2048 + col * 8 + kk] = f2bf(W1[k * 256 + col]);
}

// ---------------- Layer 1 GEMM via MFMA, LDS-double-buffered B ----------------
// Block = 256 thr = 4 waves. Wave w: rows blk*64 + w*16 .. +15, all 256 cols.
// A (x row) prefetched+converted to registers up front; B staged tile-by-tile:
// global->reg load issued one tile ahead (latency hides under MFMA), reg->LDS write
// after barrier (T14 async-split). ds_read_b128 fragments are conflict-free.
// mfma_f32_16x16x32_bf16 C/D mapping: col=l&15, row=(l>>4)*4+reg (learn_hip m89).

__global__ __launch_bounds__(256) void gemm1_kernel(
    const float* __restrict__ x, const unsigned short* __restrict__ W1s,
    const float* __restrict__ a_src1, const float* __restrict__ a_dst1,
    unsigned short* __restrict__ h1, float* __restrict__ al_src1,
    float* __restrict__ al_dst1, int N) {
    __shared__ unsigned short smB[2][8192];  // 2 x 16 KB

    const int tid = threadIdx.x;
    const int w = tid >> 6, l = tid & 63;
    const int lc = l & 15, lg = l >> 4;

    const int arow = blockIdx.x * 64 + w * 16 + lc;
    const int arowc = (arow < N) ? arow : (N - 1);

    // ---- prefetch entire A row-chunk (8 k-tiles), convert to bf16 fragments ----
    const float* xp = x + (size_t)arowc * 256 + lg * 8;
    short8 af[8];
#pragma unroll
    for (int t = 0; t < 8; t++) {
        float4 v0 = *reinterpret_cast<const float4*>(xp + t * 32);
        float4 v1 = *reinterpret_cast<const float4*>(xp + t * 32 + 4);
        af[t][0] = (short)f2bf(v0.x);
        af[t][1] = (short)f2bf(v0.y);
        af[t][2] = (short)f2bf(v0.z);
        af[t][3] = (short)f2bf(v0.w);
        af[t][4] = (short)f2bf(v1.x);
        af[t][5] = (short)f2bf(v1.y);
        af[t][6] = (short)f2bf(v1.z);
        af[t][7] = (short)f2bf(v1.w);
    }

    f32x4 acc[16];
#pragma unroll
    for (int j = 0; j < 16; j++) acc[j] = (f32x4){0.f, 0.f, 0.f, 0.f};

    // staging registers: 64 B per thread per tile
    uint4 st[4];
    const uint4* gws = reinterpret_cast<const uint4*>(W1s);

#define STAGE_LOAD(t)                         \
    {                                         \
        const uint4* gs = gws + (t) * 1024;   \
        st[0] = gs[tid];                      \
        st[1] = gs[tid + 256];                \
        st[2] = gs[tid + 512];                \
        st[3] = gs[tid + 768];                \
    }
#define STAGE_WRITE(buf)                                   \
    {                                                      \
        uint4* ls = reinterpret_cast<uint4*>(smB[(buf)]);  \
        ls[tid] = st[0];                                   \
        ls[tid + 256] = st[1];                             \
        ls[tid + 512] = st[2];                             \
        ls[tid + 768] = st[3];                             \
    }

    STAGE_LOAD(0)
    STAGE_WRITE(0)
    STAGE_LOAD(1)
    __syncthreads();  // tile 0 visible

    const unsigned short* bpbase;
#pragma unroll
    for (int t = 0; t < 8; t++) {
        // compute tile t
        bpbase = smB[t & 1] + lg * 2048 + lc * 8;
#pragma unroll
        for (int j = 0; j < 16; j++) {
            short8 bf = *reinterpret_cast<const short8*>(bpbase + j * 128);
            acc[j] = __builtin_amdgcn_mfma_f32_16x16x32_bf16(af[t], bf, acc[j], 0, 0, 0);
        }
        if (t + 1 < 8) {
            __syncthreads();  // all waves done reading buffer (t+1)&1 (tile t-1)
            STAGE_WRITE((t + 1) & 1)
            if (t + 2 < 8) STAGE_LOAD(t + 2)
            __syncthreads();  // tile t+1 visible
        }
    }
#undef STAGE_LOAD
#undef STAGE_WRITE

    // ---- epilogue: h1 store (bf16) + attention logits ----
    const int rbase = blockIdx.x * 64 + w * 16 + lg * 4;

#pragma unroll
    for (int j = 0; j < 16; j++) {
#pragma unroll
        for (int r = 0; r < 4; r++) {
            int rr = rbase + r;
            if (rr < N) h1[(size_t)rr * 256 + j * 16 + lc] = f2bf(acc[j][r]);
        }
    }

    float as_[16], ad_[16];
#pragma unroll
    for (int j = 0; j < 16; j++) {
        as_[j] = a_src1[j * 16 + lc];
        ad_[j] = a_dst1[j * 16 + lc];
    }
#pragma unroll
    for (int r = 0; r < 4; r++) {
        float s0 = 0.f, d0 = 0.f, s1 = 0.f, d1 = 0.f;
#pragma unroll
        for (int j = 0; j < 8; j++) {
            s0 += acc[j][r] * as_[j];
            d0 += acc[j][r] * ad_[j];
        }
#pragma unroll
        for (int j = 8; j < 16; j++) {
            s1 += acc[j][r] * as_[j];
            d1 += acc[j][r] * ad_[j];
        }
#pragma unroll
        for (int mask = 8; mask >= 1; mask >>= 1) {
            s0 += __shfl_xor(s0, mask, 64);
            s1 += __shfl_xor(s1, mask, 64);
            d0 += __shfl_xor(d0, mask, 64);
            d1 += __shfl_xor(d1, mask, 64);
        }
        int rr = rbase + r;
        if (lc == 0 && rr < N) {
            al_src1[rr * 2 + 0] = s0;
            al_src1[rr * 2 + 1] = s1;
            al_dst1[rr * 2 + 0] = d0;
            al_dst1[rr * 2 + 1] = d1;
        }
    }
}

// ---------------- Layer 1 aggregation (direct exp softmax, 4-edge batched) + fused L2 proj ----
// Logits provably tiny (std ~0.33): exp(e)/sum(exp(e)) == exp(e-m)/sum(exp(e-m)); no overflow
// risk below |e|~85. No online max: 1 exp per edge, no rescale chain.

__global__ __launch_bounds__(256) void agg1_kernel(
    const unsigned short* __restrict__ h1,
    const float* __restrict__ al_src1, const float* __restrict__ al_dst1,
    const int* __restrict__ offsets, const int* __restrict__ csr_src,
    const float* __restrict__ b1, const float* __restrict__ W2,
    const float* __restrict__ a_src2, const float* __restrict__ a_dst2,
    float* __restrict__ g2out, float* __restrict__ al_src2o,
    float* __restrict__ al_dst2o, int N) {
    int wid = (blockIdx.x * blockDim.x + threadIdx.x) >> 6;
    if (wid >= N) return;
    int lane = threadIdx.x & 63;
    int head = lane >> 5;
    int ch = lane * 4;

    int beg = offsets[wid], end = offsets[wid + 1];
    float aldv = al_dst1[wid * 2 + head];

    float l = 0.f, p0 = 0.f, p1 = 0.f, p2 = 0.f, p3 = 0.f;

    int e = beg;
    for (; e + 3 < end; e += 4) {
        int sa = csr_src[e];
        int sb = csr_src[e + 1];
        int sc = csr_src[e + 2];
        int sd = csr_src[e + 3];
        float la = al_src1[sa * 2 + head] + aldv;
        float lb = al_src1[sb * 2 + head] + aldv;
        float lcv = al_src1[sc * 2 + head] + aldv;
        float ld = al_src1[sd * 2 + head] + aldv;
        ushort4 ha = *reinterpret_cast<const ushort4*>(h1 + (size_t)sa * 256 + ch);
        ushort4 hb = *reinterpret_cast<const ushort4*>(h1 + (size_t)sb * 256 + ch);
        ushort4 hc = *reinterpret_cast<const ushort4*>(h1 + (size_t)sc * 256 + ch);
        ushort4 hd = *reinterpret_cast<const ushort4*>(h1 + (size_t)sd * 256 + ch);
        float wa = __expf(lrelu(la));
        float wb = __expf(lrelu(lb));
        float wc = __expf(lrelu(lcv));
        float wd = __expf(lrelu(ld));
        p0 += wa * bf2f(ha.x) + wb * bf2f(hb.x) + wc * bf2f(hc.x) + wd * bf2f(hd.x);
        p1 += wa * bf2f(ha.y) + wb * bf2f(hb.y) + wc * bf2f(hc.y) + wd * bf2f(hd.y);
        p2 += wa * bf2f(ha.z) + wb * bf2f(hb.z) + wc * bf2f(hc.z) + wd * bf2f(hd.z);
        p3 += wa * bf2f(ha.w) + wb * bf2f(hb.w) + wc * bf2f(hc.w) + wd * bf2f(hd.w);
        l += (wa + wb) + (wc + wd);
    }
    for (; e < end; ++e) {
        int sa = csr_src[e];
        float la = al_src1[sa * 2 + head] + aldv;
        ushort4 ha = *reinterpret_cast<const ushort4*>(h1 + (size_t)sa * 256 + ch);
        float wa = __expf(lrelu(la));
        p0 += wa * bf2f(ha.x);
        p1 += wa * bf2f(ha.y);
        p2 += wa * bf2f(ha.z);
        p3 += wa * bf2f(ha.w);
        l += wa;
    }

    float inv = 1.f / l;
    float4 bb = *reinterpret_cast<const float4*>(b1 + ch);
    float r0 = fmaxf(p0 * inv + bb.x, 0.f);
    float r1 = fmaxf(p1 * inv + bb.y, 0.f);
    float r2 = fmaxf(p2 * inv + bb.z, 0.f);
    float r3 = fmaxf(p3 * inv + bb.w, 0.f);

    // fused layer-2 projection: g[c] = sum_k h2[k] * W2[k][c], k distributed over wave
    float4 w0 = *reinterpret_cast<const float4*>(W2 + (size_t)(ch + 0) * 4);
    float4 w1 = *reinterpret_cast<const float4*>(W2 + (size_t)(ch + 1) * 4);
    float4 w2 = *reinterpret_cast<const float4*>(W2 + (size_t)(ch + 2) * 4);
    float4 w3 = *reinterpret_cast<const float4*>(W2 + (size_t)(ch + 3) * 4);
    float g0 = r0 * w0.x + r1 * w1.x + r2 * w2.x + r3 * w3.x;
    float g1 = r0 * w0.y + r1 * w1.y + r2 * w2.y + r3 * w3.y;
    float g2v = r0 * w0.z + r1 * w1.z + r2 * w2.z + r3 * w3.z;
    float g3 = r0 * w0.w + r1 * w1.w + r2 * w2.w + r3 * w3.w;
#pragma unroll
    for (int mask = 32; mask >= 1; mask >>= 1) {
        g0 += __shfl_xor(g0, mask, 64);
        g1 += __shfl_xor(g1, mask, 64);
        g2v += __shfl_xor(g2v, mask, 64);
        g3 += __shfl_xor(g3, mask, 64);
    }
    if (lane == 0) {
        float4 gv;
        gv.x = g0; gv.y = g1; gv.z = g2v; gv.w = g3;
        *reinterpret_cast<float4*>(g2out + (size_t)wid * 4) = gv;
        al_src2o[wid] = g0 * a_src2[0] + g1 * a_src2[1] + g2v * a_src2[2] + g3 * a_src2[3];
        al_dst2o[wid] = g0 * a_dst2[0] + g1 * a_dst2[1] + g2v * a_dst2[2] + g3 * a_dst2[3];
    }
}

// ---------------- Layer 2 aggregation (direct exp, 4-edge batched) + bias + log_softmax ------

__global__ __launch_bounds__(256) void agg2_kernel(
    const float* __restrict__ g2, const float* __restrict__ al_src2,
    const float* __restrict__ al_dst2, const int* __restrict__ offsets,
    const int* __restrict__ csr_src, const float* __restrict__ b2,
    float* __restrict__ out, int N) {
    int wid = (blockIdx.x * blockDim.x + threadIdx.x) >> 6;
    if (wid >= N) return;
    int lane = threadIdx.x & 63;

    int beg = offsets[wid], end = offsets[wid + 1];
    float aldv = al_dst2[wid];

    float l = 0.f, p0 = 0.f, p1 = 0.f, p2 = 0.f, p3 = 0.f;

    int e = beg;
    for (; e + 3 < end; e += 4) {
        int sa = csr_src[e];
        int sb = csr_src[e + 1];
        int sc = csr_src[e + 2];
        int sd = csr_src[e + 3];
        float la = al_src2[sa] + aldv;
        float lb = al_src2[sb] + aldv;
        float lcv = al_src2[sc] + aldv;
        float ld = al_src2[sd] + aldv;
        float4 ga = *reinterpret_cast<const float4*>(g2 + (size_t)sa * 4);
        float4 gb = *reinterpret_cast<const float4*>(g2 + (size_t)sb * 4);
        float4 gc = *reinterpret_cast<const float4*>(g2 + (size_t)sc * 4);
        float4 gd = *reinterpret_cast<const float4*>(g2 + (size_t)sd * 4);
        float wa = __expf(lrelu(la));
        float wb = __expf(lrelu(lb));
        float wc = __expf(lrelu(lcv));
        float wd = __expf(lrelu(ld));
        p0 += wa * ga.x + wb * gb.x + wc * gc.x + wd * gd.x;
        p1 += wa * ga.y + wb * gb.y + wc * gc.y + wd * gd.y;
        p2 += wa * ga.z + wb * gb.z + wc * gc.z + wd * gd.z;
        p3 += wa * ga.w + wb * gb.w + wc * gc.w + wd * gd.w;
        l += (wa + wb) + (wc + wd);
    }
    for (; e < end; ++e) {
        int sa = csr_src[e];
        float la = al_src2[sa] + aldv;
        float4 ga = *reinterpret_cast<const float4*>(g2 + (size_t)sa * 4);
        float wa = __expf(lrelu(la));
        p0 += wa * ga.x;
        p1 += wa * ga.y;
        p2 += wa * ga.z;
        p3 += wa * ga.w;
        l += wa;
    }

    float inv = 1.f / l;
    float r0 = p0 * inv + b2[0];
    float r1 = p1 * inv + b2[1];
    float r2 = p2 * inv + b2[2];
    float r3 = p3 * inv + b2[3];
    float mx = fmaxf(fmaxf(r0, r1), fmaxf(r2, r3));
    float s0 = __expf(r0 - mx), s1 = __expf(r1 - mx), s2 = __expf(r2 - mx), s3 = __expf(r3 - mx);
    float ls = __logf(s0 + s1 + s2 + s3);
    if (lane == 0) {
        float4 ov;
        ov.x = r0 - mx - ls;
        ov.y = r1 - mx - ls;
        ov.z = r2 - mx - ls;
        ov.w = r3 - mx - ls;
        *reinterpret_cast<float4*>(out + (size_t)wid * 4) = ov;
    }
}

// ---------------- host ----------------

extern "C" void kernel_launch(void* const* d_in, const int* in_sizes, int n_in,
                              void* d_out, int out_size, void* d_ws, size_t ws_size,
                              hipStream_t stream) {
    const float* x = (const float*)d_in[0];
    const int* edge_index = (const int*)d_in[1];
    const float* W1 = (const float*)d_in[2];
    const float* a_src1 = (const float*)d_in[3];
    const float* a_dst1 = (const float*)d_in[4];
    const float* b1 = (const float*)d_in[5];
    const float* W2 = (const float*)d_in[6];
    const float* a_src2 = (const float*)d_in[7];
    const float* a_dst2 = (const float*)d_in[8];
    const float* b2 = (const float*)d_in[9];
    float* out = (float*)d_out;

    const int N = in_sizes[0] / 256;
    const int E = in_sizes[1] / 2;
    const int EN = E + N;
    const int* src_idx = edge_index;
    const int* dst_idx = edge_index + E;

    char* ws = (char*)d_ws;
    size_t off = 0;
    auto alloc = [&](size_t bytes) -> char* {
        char* p = ws + off;
        off += (bytes + 255) & ~(size_t)255;
        return p;
    };
    unsigned short* h1 = (unsigned short*)alloc((size_t)N * 256 * 2);
    unsigned short* W1s = (unsigned short*)alloc((size_t)256 * 256 * 2);
    float* al_src1 = (float*)alloc((size_t)N * 2 * 4);
    float* al_dst1 = (float*)alloc((size_t)N * 2 * 4);
    float* g2 = (float*)alloc((size_t)N * 4 * 4);
    float* al_src2 = (float*)alloc((size_t)N * 4);
    float* al_dst2 = (float*)alloc((size_t)N * 4);
    int* offsets = (int*)alloc((size_t)(N + 1) * 4);
    int* cursor = (int*)alloc((size_t)N * 4);
    int* csr_src = (int*)alloc((size_t)EN * 4);
    int* blockSums = (int*)alloc(128 * 4);

    hipMemsetAsync(cursor, 0, (size_t)N * 4, stream);

    prep_w1s<<<256, 256, 0, stream>>>(W1, W1s);

    int hb = (EN + 255) / 256;
    hist_kernel<<<hb, 256, 0, stream>>>(dst_idx, cursor, E, N);

    int nb = (N + SCAN_ELEMS - 1) / SCAN_ELEMS;
    scan_blocks_kernel<<<nb, SCAN_TPB, 0, stream>>>(cursor, offsets, blockSums, N);
    scan_sums_kernel<<<1, 128, 0, stream>>>(blockSums, nb);
    scan_finalize_kernel<<<nb, SCAN_TPB, 0, stream>>>(offsets, blockSums, cursor, N, EN);

    scatter_kernel<<<hb, 256, 0, stream>>>(src_idx, dst_idx, cursor, csr_src, E, N);

    int gb = (N + 63) / 64;
    gemm1_kernel<<<gb, 256, 0, stream>>>(x, W1s, a_src1, a_dst1, h1, al_src1, al_dst1, N);

    int ab = (N + 3) / 4;
    agg1_kernel<<<ab, 256, 0, stream>>>(h1, al_src1, al_dst1, offsets, csr_src, b1, W2,
                                        a_src2, a_dst2, g2, al_src2, al_dst2, N);
    agg2_kernel<<<ab, 256, 0, stream>>>(g2, al_src2, al_dst2, offsets, csr_src, b2, out, N);
}

// Round 9
// 627.172 us; speedup vs baseline: 1.4060x; 1.0578x over previous
//
#include <hip/hip_runtime.h>
#include <hip/hip_bf16.h>

#define NEG_SLOPE 0.2f
#define SCAN_TPB 256
#define SCAN_VPT 4
#define SCAN_ELEMS (SCAN_TPB * SCAN_VPT)

typedef __attribute__((ext_vector_type(8))) short short8;
typedef __attribute__((ext_vector_type(4))) float f32x4;

static __device__ __forceinline__ unsigned short f2bf(float v) {
    __hip_bfloat16 b = __float2bfloat16(v);
    return *reinterpret_cast<unsigned short*>(&b);
}
static __device__ __forceinline__ float bf2f(unsigned short u) {
    unsigned int x = ((unsigned int)u) << 16;
    return __uint_as_float(x);
}
static __device__ __forceinline__ float lrelu(float v) {
    return (v > 0.f) ? v : NEG_SLOPE * v;
}

// ---------------- CSR build ----------------

__global__ void hist_kernel(const int* __restrict__ dst_idx, int* __restrict__ count,
                            int E, int N) {
    int e = blockIdx.x * blockDim.x + threadIdx.x;
    int EN = E + N;
    if (e >= EN) return;
    int d = (e < E) ? dst_idx[e] : (e - E);
    atomicAdd(&count[d], 1);
}

__global__ void scan_blocks_kernel(const int* __restrict__ count, int* __restrict__ local_ex,
                                   int* __restrict__ blockSums, int n) {
    __shared__ int sm[SCAN_TPB];
    int tid = threadIdx.x;
    int base = blockIdx.x * SCAN_ELEMS + tid * SCAN_VPT;
    int v[SCAN_VPT];
    int s = 0;
#pragma unroll
    for (int i = 0; i < SCAN_VPT; i++) {
        v[i] = (base + i < n) ? count[base + i] : 0;
        s += v[i];
    }
    sm[tid] = s;
    __syncthreads();
#pragma unroll
    for (int off = 1; off < SCAN_TPB; off <<= 1) {
        int t = (tid >= off) ? sm[tid - off] : 0;
        __syncthreads();
        sm[tid] += t;
        __syncthreads();
    }
    int ex = sm[tid] - s;
#pragma unroll
    for (int i = 0; i < SCAN_VPT; i++) {
        if (base + i < n) local_ex[base + i] = ex;
        ex += v[i];
    }
    if (tid == SCAN_TPB - 1) blockSums[blockIdx.x] = sm[tid];
}

__global__ void scan_sums_kernel(int* __restrict__ blockSums, int nb) {
    __shared__ int sm[128];
    int tid = threadIdx.x;
    int v = (tid < nb) ? blockSums[tid] : 0;
    sm[tid] = v;
    __syncthreads();
    for (int off = 1; off < 128; off <<= 1) {
        int t = (tid >= off) ? sm[tid - off] : 0;
        __syncthreads();
        sm[tid] += t;
        __syncthreads();
    }
    if (tid < nb) blockSums[tid] = sm[tid] - v;
}

__global__ void scan_finalize_kernel(int* __restrict__ offsets, const int* __restrict__ blockSums,
                                     int* __restrict__ cursor, int n, int total) {
    int tid = threadIdx.x;
    int base = blockIdx.x * SCAN_ELEMS + tid * SCAN_VPT;
    int add = blockSums[blockIdx.x];
#pragma unroll
    for (int i = 0; i < SCAN_VPT; i++) {
        int idx = base + i;
        if (idx < n) {
            int val = offsets[idx] + add;
            offsets[idx] = val;
            cursor[idx] = val;
        }
    }
    if (blockIdx.x == 0 && tid == 0) offsets[n] = total;
}

__global__ void scatter_kernel(const int* __restrict__ src_idx, const int* __restrict__ dst_idx,
                               int* __restrict__ cursor, int* __restrict__ csr_src,
                               int E, int N) {
    int e = blockIdx.x * blockDim.x + threadIdx.x;
    int EN = E + N;
    if (e >= EN) return;
    int s, d;
    if (e < E) {
        s = src_idx[e];
        d = dst_idx[e];
    } else {
        s = d = e - E;
    }
    int pos = atomicAdd(&cursor[d], 1);
    csr_src[pos] = s;
}

// ---------------- x convert: xs = bf16(x), streaming ----------------

__global__ __launch_bounds__(256) void prep_xs(const float* __restrict__ x,
                                               unsigned short* __restrict__ xs, int total8) {
    int i = blockIdx.x * 256 + threadIdx.x;
    if (i >= total8) return;
    float4 v0 = *reinterpret_cast<const float4*>(x + (size_t)i * 8);
    float4 v1 = *reinterpret_cast<const float4*>(x + (size_t)i * 8 + 4);
    ushort4 u0, u1;
    u0.x = f2bf(v0.x); u0.y = f2bf(v0.y); u0.z = f2bf(v0.z); u0.w = f2bf(v0.w);
    u1.x = f2bf(v1.x); u1.y = f2bf(v1.y); u1.z = f2bf(v1.z); u1.w = f2bf(v1.w);
    *reinterpret_cast<ushort4*>(xs + (size_t)i * 8) = u0;
    *reinterpret_cast<ushort4*>(xs + (size_t)i * 8 + 4) = u1;
}

// ---------------- W1 repack: W1s[t][lg][lc][j][kk] bf16 ----------------
// k = t*32 + lg*8 + kk, col = j*16 + lc. Lane (lc,lg) tile t reads a CONTIGUOUS
// 256-B run: base t*8192 + lg*2048 + lc*128, fragment j at +j*8 shorts.

__global__ __launch_bounds__(256) void prep_w1s(const float* __restrict__ W1,
                                                unsigned short* __restrict__ W1s) {
    int idx = blockIdx.x * 256 + threadIdx.x;  // 65536 total
    int col = idx & 255;
    int k = idx >> 8;
    int t = k >> 5, lg = (k >> 3) & 3, kk = k & 7;
    int j = col >> 4, lc = col & 15;
    W1s[t * 8192 + lg * 2048 + lc * 128 + j * 8 + kk] = f2bf(W1[k * 256 + col]);
}

// ---------------- Layer 1 GEMM via MFMA: h1 = xs @ W1, + logits ----------------
// Block = 256 thr = 4 waves, no LDS, no barriers. Wave w: rows blk*64+w*16..+15, 256 cols.
// A: 8 tiles prefetched as ushort8 (16 VGPR). B: L2-direct, per-lane contiguous 256-B
// runs per tile -> 16 independent 16-B loads, deep MLP, no spill (launch_bounds caps 128).
// mfma_f32_16x16x32_bf16 C/D: col=l&15, row=(l>>4)*4+reg (learn_hip m89).

__global__ __launch_bounds__(256, 4) void gemm1_kernel(
    const unsigned short* __restrict__ xs, const unsigned short* __restrict__ W1s,
    const float* __restrict__ a_src1, const float* __restrict__ a_dst1,
    unsigned short* __restrict__ h1, float* __restrict__ al_src1,
    float* __restrict__ al_dst1, int N) {
    const int tid = threadIdx.x;
    const int w = tid >> 6, l = tid & 63;
    const int lc = l & 15, lg = l >> 4;

    const int arow = blockIdx.x * 64 + w * 16 + lc;
    const int arowc = (arow < N) ? arow : (N - 1);

    // prefetch all 8 A fragments (128 B/lane in flight)
    const unsigned short* xp = xs + (size_t)arowc * 256 + lg * 8;
    short8 af[8];
#pragma unroll
    for (int t = 0; t < 8; t++) af[t] = *reinterpret_cast<const short8*>(xp + t * 32);

    f32x4 acc[16];
#pragma unroll
    for (int j = 0; j < 16; j++) acc[j] = (f32x4){0.f, 0.f, 0.f, 0.f};

    const unsigned short* wbase = W1s + lg * 2048 + lc * 128;
#pragma unroll
    for (int t = 0; t < 8; t++) {
        const unsigned short* wp = wbase + t * 8192;
#pragma unroll
        for (int j = 0; j < 16; j++) {
            short8 bf = *reinterpret_cast<const short8*>(wp + j * 8);
            acc[j] = __builtin_amdgcn_mfma_f32_16x16x32_bf16(af[t], bf, acc[j], 0, 0, 0);
        }
    }

    // epilogue: h1 store (bf16) + attention logits
    const int rbase = blockIdx.x * 64 + w * 16 + lg * 4;

#pragma unroll
    for (int j = 0; j < 16; j++) {
#pragma unroll
        for (int r = 0; r < 4; r++) {
            int rr = rbase + r;
            if (rr < N) h1[(size_t)rr * 256 + j * 16 + lc] = f2bf(acc[j][r]);
        }
    }

    float as_[16], ad_[16];
#pragma unroll
    for (int j = 0; j < 16; j++) {
        as_[j] = a_src1[j * 16 + lc];
        ad_[j] = a_dst1[j * 16 + lc];
    }
#pragma unroll
    for (int r = 0; r < 4; r++) {
        float s0 = 0.f, d0 = 0.f, s1 = 0.f, d1 = 0.f;
#pragma unroll
        for (int j = 0; j < 8; j++) {
            s0 += acc[j][r] * as_[j];
            d0 += acc[j][r] * ad_[j];
        }
#pragma unroll
        for (int j = 8; j < 16; j++) {
            s1 += acc[j][r] * as_[j];
            d1 += acc[j][r] * ad_[j];
        }
#pragma unroll
        for (int mask = 8; mask >= 1; mask >>= 1) {
            s0 += __shfl_xor(s0, mask, 64);
            s1 += __shfl_xor(s1, mask, 64);
            d0 += __shfl_xor(d0, mask, 64);
            d1 += __shfl_xor(d1, mask, 64);
        }
        int rr = rbase + r;
        if (lc == 0 && rr < N) {
            al_src1[rr * 2 + 0] = s0;
            al_src1[rr * 2 + 1] = s1;
            al_dst1[rr * 2 + 0] = d0;
            al_dst1[rr * 2 + 1] = d1;
        }
    }
}

// ---------------- Layer 1 aggregation (direct exp softmax, 4-edge batched) + fused L2 proj ----

__global__ __launch_bounds__(256) void agg1_kernel(
    const unsigned short* __restrict__ h1,
    const float* __restrict__ al_src1, const float* __restrict__ al_dst1,
    const int* __restrict__ offsets, const int* __restrict__ csr_src,
    const float* __restrict__ b1, const float* __restrict__ W2,
    const float* __restrict__ a_src2, const float* __restrict__ a_dst2,
    float* __restrict__ g2out, float* __restrict__ al_src2o,
    float* __restrict__ al_dst2o, int N) {
    int wid = (blockIdx.x * blockDim.x + threadIdx.x) >> 6;
    if (wid >= N) return;
    int lane = threadIdx.x & 63;
    int head = lane >> 5;
    int ch = lane * 4;

    int beg = offsets[wid], end = offsets[wid + 1];
    float aldv = al_dst1[wid * 2 + head];

    float l = 0.f, p0 = 0.f, p1 = 0.f, p2 = 0.f, p3 = 0.f;

    int e = beg;
    for (; e + 3 < end; e += 4) {
        int sa = csr_src[e];
        int sb = csr_src[e + 1];
        int sc = csr_src[e + 2];
        int sd = csr_src[e + 3];
        float la = al_src1[sa * 2 + head] + aldv;
        float lb = al_src1[sb * 2 + head] + aldv;
        float lcv = al_src1[sc * 2 + head] + aldv;
        float ld = al_src1[sd * 2 + head] + aldv;
        ushort4 ha = *reinterpret_cast<const ushort4*>(h1 + (size_t)sa * 256 + ch);
        ushort4 hb = *reinterpret_cast<const ushort4*>(h1 + (size_t)sb * 256 + ch);
        ushort4 hc = *reinterpret_cast<const ushort4*>(h1 + (size_t)sc * 256 + ch);
        ushort4 hd = *reinterpret_cast<const ushort4*>(h1 + (size_t)sd * 256 + ch);
        float wa = __expf(lrelu(la));
        float wb = __expf(lrelu(lb));
        float wc = __expf(lrelu(lcv));
        float wd = __expf(lrelu(ld));
        p0 += wa * bf2f(ha.x) + wb * bf2f(hb.x) + wc * bf2f(hc.x) + wd * bf2f(hd.x);
        p1 += wa * bf2f(ha.y) + wb * bf2f(hb.y) + wc * bf2f(hc.y) + wd * bf2f(hd.y);
        p2 += wa * bf2f(ha.z) + wb * bf2f(hb.z) + wc * bf2f(hc.z) + wd * bf2f(hd.z);
        p3 += wa * bf2f(ha.w) + wb * bf2f(hb.w) + wc * bf2f(hc.w) + wd * bf2f(hd.w);
        l += (wa + wb) + (wc + wd);
    }
    for (; e < end; ++e) {
        int sa = csr_src[e];
        float la = al_src1[sa * 2 + head] + aldv;
        ushort4 ha = *reinterpret_cast<const ushort4*>(h1 + (size_t)sa * 256 + ch);
        float wa = __expf(lrelu(la));
        p0 += wa * bf2f(ha.x);
        p1 += wa * bf2f(ha.y);
        p2 += wa * bf2f(ha.z);
        p3 += wa * bf2f(ha.w);
        l += wa;
    }

    float inv = 1.f / l;
    float4 bb = *reinterpret_cast<const float4*>(b1 + ch);
    float r0 = fmaxf(p0 * inv + bb.x, 0.f);
    float r1 = fmaxf(p1 * inv + bb.y, 0.f);
    float r2 = fmaxf(p2 * inv + bb.z, 0.f);
    float r3 = fmaxf(p3 * inv + bb.w, 0.f);

    float4 w0 = *reinterpret_cast<const float4*>(W2 + (size_t)(ch + 0) * 4);
    float4 w1 = *reinterpret_cast<const float4*>(W2 + (size_t)(ch + 1) * 4);
    float4 w2 = *reinterpret_cast<const float4*>(W2 + (size_t)(ch + 2) * 4);
    float4 w3 = *reinterpret_cast<const float4*>(W2 + (size_t)(ch + 3) * 4);
    float g0 = r0 * w0.x + r1 * w1.x + r2 * w2.x + r3 * w3.x;
    float g1 = r0 * w0.y + r1 * w1.y + r2 * w2.y + r3 * w3.y;
    float g2v = r0 * w0.z + r1 * w1.z + r2 * w2.z + r3 * w3.z;
    float g3 = r0 * w0.w + r1 * w1.w + r2 * w2.w + r3 * w3.w;
#pragma unroll
    for (int mask = 32; mask >= 1; mask >>= 1) {
        g0 += __shfl_xor(g0, mask, 64);
        g1 += __shfl_xor(g1, mask, 64);
        g2v += __shfl_xor(g2v, mask, 64);
        g3 += __shfl_xor(g3, mask, 64);
    }
    if (lane == 0) {
        float4 gv;
        gv.x = g0; gv.y = g1; gv.z = g2v; gv.w = g3;
        *reinterpret_cast<float4*>(g2out + (size_t)wid * 4) = gv;
        al_src2o[wid] = g0 * a_src2[0] + g1 * a_src2[1] + g2v * a_src2[2] + g3 * a_src2[3];
        al_dst2o[wid] = g0 * a_dst2[0] + g1 * a_dst2[1] + g2v * a_dst2[2] + g3 * a_dst2[3];
    }
}

// ---------------- Layer 2 aggregation: THREAD per node (4 channels only) ----------------
// Wave-per-node wasted 16x lanes. g2 (1.6 MB) + al_src2 (0.4 MB) are L2-resident.

__global__ __launch_bounds__(256) void agg2_kernel(
    const float* __restrict__ g2, const float* __restrict__ al_src2,
    const float* __restrict__ al_dst2, const int* __restrict__ offsets,
    const int* __restrict__ csr_src, const float* __restrict__ b2,
    float* __restrict__ out, int N) {
    int nid = blockIdx.x * 256 + threadIdx.x;
    if (nid >= N) return;

    int beg = offsets[nid], end = offsets[nid + 1];
    float aldv = al_dst2[nid];

    float l = 0.f, p0 = 0.f, p1 = 0.f, p2 = 0.f, p3 = 0.f;

    int e = beg;
    for (; e + 3 < end; e += 4) {
        int sa = csr_src[e];
        int sb = csr_src[e + 1];
        int sc = csr_src[e + 2];
        int sd = csr_src[e + 3];
        float la = al_src2[sa] + aldv;
        float lb = al_src2[sb] + aldv;
        float lcv = al_src2[sc] + aldv;
        float ld = al_src2[sd] + aldv;
        float4 ga = *reinterpret_cast<const float4*>(g2 + (size_t)sa * 4);
        float4 gb = *reinterpret_cast<const float4*>(g2 + (size_t)sb * 4);
        float4 gc = *reinterpret_cast<const float4*>(g2 + (size_t)sc * 4);
        float4 gd = *reinterpret_cast<const float4*>(g2 + (size_t)sd * 4);
        float wa = __expf(lrelu(la));
        float wb = __expf(lrelu(lb));
        float wc = __expf(lrelu(lcv));
        float wd = __expf(lrelu(ld));
        p0 += wa * ga.x + wb * gb.x + wc * gc.x + wd * gd.x;
        p1 += wa * ga.y + wb * gb.y + wc * gc.y + wd * gd.y;
        p2 += wa * ga.z + wb * gb.z + wc * gc.z + wd * gd.z;
        p3 += wa * ga.w + wb * gb.w + wc * gc.w + wd * gd.w;
        l += (wa + wb) + (wc + wd);
    }
    for (; e < end; ++e) {
        int sa = csr_src[e];
        float la = al_src2[sa] + aldv;
        float4 ga = *reinterpret_cast<const float4*>(g2 + (size_t)sa * 4);
        float wa = __expf(lrelu(la));
        p0 += wa * ga.x;
        p1 += wa * ga.y;
        p2 += wa * ga.z;
        p3 += wa * ga.w;
        l += wa;
    }

    float inv = 1.f / l;
    float r0 = p0 * inv + b2[0];
    float r1 = p1 * inv + b2[1];
    float r2 = p2 * inv + b2[2];
    float r3 = p3 * inv + b2[3];
    float mx = fmaxf(fmaxf(r0, r1), fmaxf(r2, r3));
    float s0 = __expf(r0 - mx), s1 = __expf(r1 - mx), s2 = __expf(r2 - mx), s3 = __expf(r3 - mx);
    float ls = __logf(s0 + s1 + s2 + s3);
    float4 ov;
    ov.x = r0 - mx - ls;
    ov.y = r1 - mx - ls;
    ov.z = r2 - mx - ls;
    ov.w = r3 - mx - ls;
    *reinterpret_cast<float4*>(out + (size_t)nid * 4) = ov;
}

// ---------------- host ----------------

extern "C" void kernel_launch(void* const* d_in, const int* in_sizes, int n_in,
                              void* d_out, int out_size, void* d_ws, size_t ws_size,
                              hipStream_t stream) {
    const float* x = (const float*)d_in[0];
    const int* edge_index = (const int*)d_in[1];
    const float* W1 = (const float*)d_in[2];
    const float* a_src1 = (const float*)d_in[3];
    const float* a_dst1 = (const float*)d_in[4];
    const float* b1 = (const float*)d_in[5];
    const float* W2 = (const float*)d_in[6];
    const float* a_src2 = (const float*)d_in[7];
    const float* a_dst2 = (const float*)d_in[8];
    const float* b2 = (const float*)d_in[9];
    float* out = (float*)d_out;

    const int N = in_sizes[0] / 256;
    const int E = in_sizes[1] / 2;
    const int EN = E + N;
    const int* src_idx = edge_index;
    const int* dst_idx = edge_index + E;

    char* ws = (char*)d_ws;
    size_t off = 0;
    auto alloc = [&](size_t bytes) -> char* {
        char* p = ws + off;
        off += (bytes + 255) & ~(size_t)255;
        return p;
    };
    unsigned short* h1 = (unsigned short*)alloc((size_t)N * 256 * 2);
    unsigned short* xs = (unsigned short*)alloc((size_t)N * 256 * 2);
    unsigned short* W1s = (unsigned short*)alloc((size_t)256 * 256 * 2);
    float* al_src1 = (float*)alloc((size_t)N * 2 * 4);
    float* al_dst1 = (float*)alloc((size_t)N * 2 * 4);
    float* g2 = (float*)alloc((size_t)N * 4 * 4);
    float* al_src2 = (float*)alloc((size_t)N * 4);
    float* al_dst2 = (float*)alloc((size_t)N * 4);
    int* offsets = (int*)alloc((size_t)(N + 1) * 4);
    int* cursor = (int*)alloc((size_t)N * 4);
    int* csr_src = (int*)alloc((size_t)EN * 4);
    int* blockSums = (int*)alloc(128 * 4);

    hipMemsetAsync(cursor, 0, (size_t)N * 4, stream);

    prep_w1s<<<256, 256, 0, stream>>>(W1, W1s);
    int total8 = N * 32;  // N*256/8
    prep_xs<<<(total8 + 255) / 256, 256, 0, stream>>>(x, xs, total8);

    int hb = (EN + 255) / 256;
    hist_kernel<<<hb, 256, 0, stream>>>(dst_idx, cursor, E, N);

    int nb = (N + SCAN_ELEMS - 1) / SCAN_ELEMS;
    scan_blocks_kernel<<<nb, SCAN_TPB, 0, stream>>>(cursor, offsets, blockSums, N);
    scan_sums_kernel<<<1, 128, 0, stream>>>(blockSums, nb);
    scan_finalize_kernel<<<nb, SCAN_TPB, 0, stream>>>(offsets, blockSums, cursor, N, EN);

    scatter_kernel<<<hb, 256, 0, stream>>>(src_idx, dst_idx, cursor, csr_src, E, N);

    int gb = (N + 63) / 64;
    gemm1_kernel<<<gb, 256, 0, stream>>>(xs, W1s, a_src1, a_dst1, h1, al_src1, al_dst1, N);

    int ab = (N + 3) / 4;
    agg1_kernel<<<ab, 256, 0, stream>>>(h1, al_src1, al_dst1, offsets, csr_src, b1, W2,
                                        a_src2, a_dst2, g2, al_src2, al_dst2, N);
    agg2_kernel<<<(N + 255) / 256, 256, 0, stream>>>(g2, al_src2, al_dst2, offsets, csr_src,
                                                     b2, out, N);
}

// Round 15
// 590.002 us; speedup vs baseline: 1.4945x; 1.0630x over previous
//
#include <hip/hip_runtime.h>
#include <hip/hip_bf16.h>

#define NEG_SLOPE 0.2f
#define SCAN_TPB 256
#define SCAN_VPT 4
#define SCAN_ELEMS (SCAN_TPB * SCAN_VPT)
#define BIN_CHUNK 2048  // edges per bin_kernel block (8 per thread)

typedef __attribute__((ext_vector_type(8))) short short8;
typedef __attribute__((ext_vector_type(4))) float f32x4;

static __device__ __forceinline__ unsigned short f2bf(float v) {
    __hip_bfloat16 b = __float2bfloat16(v);
    return *reinterpret_cast<unsigned short*>(&b);
}
static __device__ __forceinline__ float bf2f(unsigned short u) {
    unsigned int x = ((unsigned int)u) << 16;
    return __uint_as_float(x);
}
static __device__ __forceinline__ float lrelu(float v) {
    return (v > 0.f) ? v : NEG_SLOPE * v;
}

// ---------------- CSR build: hist + scan ----------------

__global__ void hist_kernel(const int* __restrict__ dst_idx, int* __restrict__ count,
                            int E, int N) {
    int e = blockIdx.x * blockDim.x + threadIdx.x;
    int EN = E + N;
    if (e >= EN) return;
    int d = (e < E) ? dst_idx[e] : (e - E);
    atomicAdd(&count[d], 1);
}

__global__ void scan_blocks_kernel(const int* __restrict__ count, int* __restrict__ local_ex,
                                   int* __restrict__ blockSums, int n) {
    __shared__ int sm[SCAN_TPB];
    int tid = threadIdx.x;
    int base = blockIdx.x * SCAN_ELEMS + tid * SCAN_VPT;
    int v[SCAN_VPT];
    int s = 0;
#pragma unroll
    for (int i = 0; i < SCAN_VPT; i++) {
        v[i] = (base + i < n) ? count[base + i] : 0;
        s += v[i];
    }
    sm[tid] = s;
    __syncthreads();
#pragma unroll
    for (int off = 1; off < SCAN_TPB; off <<= 1) {
        int t = (tid >= off) ? sm[tid - off] : 0;
        __syncthreads();
        sm[tid] += t;
        __syncthreads();
    }
    int ex = sm[tid] - s;
#pragma unroll
    for (int i = 0; i < SCAN_VPT; i++) {
        if (base + i < n) local_ex[base + i] = ex;
        ex += v[i];
    }
    if (tid == SCAN_TPB - 1) blockSums[blockIdx.x] = sm[tid];
}

__global__ void scan_sums_kernel(int* __restrict__ blockSums, int nb) {
    __shared__ int sm[128];
    int tid = threadIdx.x;
    int v = (tid < nb) ? blockSums[tid] : 0;
    sm[tid] = v;
    __syncthreads();
    for (int off = 1; off < 128; off <<= 1) {
        int t = (tid >= off) ? sm[tid - off] : 0;
        __syncthreads();
        sm[tid] += t;
        __syncthreads();
    }
    if (tid < nb) blockSums[tid] = sm[tid] - v;
}

__global__ void scan_finalize_kernel(int* __restrict__ offsets, const int* __restrict__ blockSums,
                                     int* __restrict__ cursor, int n, int total) {
    int tid = threadIdx.x;
    int base = blockIdx.x * SCAN_ELEMS + tid * SCAN_VPT;
    int add = blockSums[blockIdx.x];
#pragma unroll
    for (int i = 0; i < SCAN_VPT; i++) {
        int idx = base + i;
        if (idx < n) {
            int val = offsets[idx] + add;
            offsets[idx] = val;
            cursor[idx] = val;
        }
    }
    if (blockIdx.x == 0 && tid == 0) offsets[n] = total;
}

// ---------------- CSR build: binned two-phase scatter ----------------
// Bucket = dst >> 9 (512-node ranges). Bucket base in csr = offsets[b*512] (dst-sorted CSR).

__global__ void bucket_init_kernel(const int* __restrict__ offsets, int* __restrict__ bucketCursor,
                                   int nbuck, int N) {
    int tid = threadIdx.x;
    if (tid < nbuck) bucketCursor[tid] = offsets[tid << 9];
}

// Phase A: rank edges into buckets via LDS, reserve runs, write (src,dst) pairs clustered.
__global__ __launch_bounds__(256) void bin_kernel(const int* __restrict__ src_idx,
                                                  const int* __restrict__ dst_idx,
                                                  int* __restrict__ bucketCursor,
                                                  int2* __restrict__ pairbuf, int E, int N) {
    __shared__ int cnt[256];
    __shared__ int gbase[256];
    const int tid = threadIdx.x;
    const int EN = E + N;
    const int nbuck = (N + 511) >> 9;

    cnt[tid] = 0;
    __syncthreads();

    int e0 = blockIdx.x * BIN_CHUNK + tid * 8;
    int sv[8], dv[8], bk[8], rk[8];
#pragma unroll
    for (int i = 0; i < 8; i++) {
        int e = e0 + i;
        if (e < EN) {
            int s, d;
            if (e < E) {
                s = src_idx[e];
                d = dst_idx[e];
            } else {
                s = d = e - E;
            }
            sv[i] = s;
            dv[i] = d;
            bk[i] = d >> 9;
            rk[i] = atomicAdd(&cnt[bk[i]], 1);
        } else {
            bk[i] = -1;
        }
    }
    __syncthreads();
    if (tid < nbuck && cnt[tid] > 0) gbase[tid] = atomicAdd(&bucketCursor[tid], cnt[tid]);
    __syncthreads();
#pragma unroll
    for (int i = 0; i < 8; i++) {
        if (bk[i] >= 0) {
            int2 p;
            p.x = sv[i];
            p.y = dv[i];
            pairbuf[gbase[bk[i]] + rk[i]] = p;
        }
    }
}

// Phase B: one block per bucket; fine scatter within the bucket's ~35 KB csr region.
__global__ __launch_bounds__(256) void sortb_kernel(const int2* __restrict__ pairbuf,
                                                    const int* __restrict__ offsets,
                                                    int* __restrict__ cursor,
                                                    int* __restrict__ csr_src, int N) {
    int b = blockIdx.x;
    int nodeEnd = (b + 1) << 9;
    if (nodeEnd > N) nodeEnd = N;
    int pBeg = offsets[b << 9];
    int pEnd = offsets[nodeEnd];
    for (int i = pBeg + threadIdx.x; i < pEnd; i += 256) {
        int2 p = pairbuf[i];
        int pos = atomicAdd(&cursor[p.y], 1);
        csr_src[pos] = p.x;
    }
}

// ---------------- x convert: xs = bf16(x), streaming ----------------

__global__ __launch_bounds__(256) void prep_xs(const float* __restrict__ x,
                                               unsigned short* __restrict__ xs, int total8) {
    int i = blockIdx.x * 256 + threadIdx.x;
    if (i >= total8) return;
    float4 v0 = *reinterpret_cast<const float4*>(x + (size_t)i * 8);
    float4 v1 = *reinterpret_cast<const float4*>(x + (size_t)i * 8 + 4);
    ushort4 u0, u1;
    u0.x = f2bf(v0.x); u0.y = f2bf(v0.y); u0.z = f2bf(v0.z); u0.w = f2bf(v0.w);
    u1.x = f2bf(v1.x); u1.y = f2bf(v1.y); u1.z = f2bf(v1.z); u1.w = f2bf(v1.w);
    *reinterpret_cast<ushort4*>(xs + (size_t)i * 8) = u0;
    *reinterpret_cast<ushort4*>(xs + (size_t)i * 8 + 4) = u1;
}

// ---------------- W1 repack: W1s[t][lg][lc][j][kk] bf16 ----------------
// k = t*32 + lg*8 + kk, col = j*16 + lc. Lane (lc,lg) tile t, col-half jh reads a
// contiguous 128-B run: t*8192 + lg*2048 + lc*128 + jh*64, fragment j at +j*8 shorts.

__global__ __launch_bounds__(256) void prep_w1s(const float* __restrict__ W1,
                                                unsigned short* __restrict__ W1s) {
    int idx = blockIdx.x * 256 + threadIdx.x;  // 65536 total
    int col = idx & 255;
    int k = idx >> 8;
    int t = k >> 5, lg = (k >> 3) & 3, kk = k & 7;
    int j = col >> 4, lc = col & 15;
    W1s[t * 8192 + lg * 2048 + lc * 128 + j * 8 + kk] = f2bf(W1[k * 256 + col]);
}

// ---------------- Layer 1 GEMM via MFMA: h1 = xs @ W1, + logits ----------------
// Column-split: block = 4 waves x (16 rows x 128 cols). blockIdx: rb = >>1, jh = &1.
// Head jh's logit cols [jh*128, jh*128+128) live entirely in col-half jh.
// acc = 8 frags (32 VGPR) -> deeper occupancy for latency hiding.
// mfma_f32_16x16x32_bf16 C/D: col=l&15, row=(l>>4)*4+reg (learn_hip m89).

__global__ __launch_bounds__(256, 4) void gemm1_kernel(
    const unsigned short* __restrict__ xs, const unsigned short* __restrict__ W1s,
    const float* __restrict__ a_src1, const float* __restrict__ a_dst1,
    unsigned short* __restrict__ h1, float* __restrict__ al_src1,
    float* __restrict__ al_dst1, int N) {
    const int tid = threadIdx.x;
    const int w = tid >> 6, l = tid & 63;
    const int lc = l & 15, lg = l >> 4;
    const int rb = blockIdx.x >> 1, jh = blockIdx.x & 1;

    const int arow = rb * 64 + w * 16 + lc;
    const int arowc = (arow < N) ? arow : (N - 1);

    // prefetch all 8 A fragments (128 B/lane in flight)
    const unsigned short* xp = xs + (size_t)arowc * 256 + lg * 8;
    short8 af[8];
#pragma unroll
    for (int t = 0; t < 8; t++) af[t] = *reinterpret_cast<const short8*>(xp + t * 32);

    f32x4 acc[8];
#pragma unroll
    for (int j = 0; j < 8; j++) acc[j] = (f32x4){0.f, 0.f, 0.f, 0.f};

    const unsigned short* wbase = W1s + lg * 2048 + lc * 128 + jh * 64;
#pragma unroll
    for (int t = 0; t < 8; t++) {
        const unsigned short* wp = wbase + t * 8192;
#pragma unroll
        for (int j = 0; j < 8; j++) {
            short8 bf = *reinterpret_cast<const short8*>(wp + j * 8);
            acc[j] = __builtin_amdgcn_mfma_f32_16x16x32_bf16(af[t], bf, acc[j], 0, 0, 0);
        }
    }

    // epilogue: h1 store (bf16, cols jh*128 + j*16 + lc) + head-jh logits
    const int rbase = rb * 64 + w * 16 + lg * 4;

#pragma unroll
    for (int j = 0; j < 8; j++) {
#pragma unroll
        for (int r = 0; r < 4; r++) {
            int rr = rbase + r;
            if (rr < N) h1[(size_t)rr * 256 + jh * 128 + j * 16 + lc] = f2bf(acc[j][r]);
        }
    }

    float as_[8], ad_[8];
#pragma unroll
    for (int j = 0; j < 8; j++) {
        as_[j] = a_src1[jh * 128 + j * 16 + lc];
        ad_[j] = a_dst1[jh * 128 + j * 16 + lc];
    }
#pragma unroll
    for (int r = 0; r < 4; r++) {
        float s0 = 0.f, d0 = 0.f;
#pragma unroll
        for (int j = 0; j < 8; j++) {
            s0 += acc[j][r] * as_[j];
            d0 += acc[j][r] * ad_[j];
        }
#pragma unroll
        for (int mask = 8; mask >= 1; mask >>= 1) {
            s0 += __shfl_xor(s0, mask, 64);
            d0 += __shfl_xor(d0, mask, 64);
        }
        int rr = rbase + r;
        if (lc == 0 && rr < N) {
            al_src1[rr * 2 + jh] = s0;
            al_dst1[rr * 2 + jh] = d0;
        }
    }
}

// ---------------- Layer 1 aggregation (direct exp softmax, 4-edge batched) + fused L2 proj ----

__global__ __launch_bounds__(256) void agg1_kernel(
    const unsigned short* __restrict__ h1,
    const float* __restrict__ al_src1, const float* __restrict__ al_dst1,
    const int* __restrict__ offsets, const int* __restrict__ csr_src,
    const float* __restrict__ b1, const float* __restrict__ W2,
    const float* __restrict__ a_src2, const float* __restrict__ a_dst2,
    float* __restrict__ g2out, float* __restrict__ al_src2o,
    float* __restrict__ al_dst2o, int N) {
    int wid = (blockIdx.x * blockDim.x + threadIdx.x) >> 6;
    if (wid >= N) return;
    int lane = threadIdx.x & 63;
    int head = lane >> 5;
    int ch = lane * 4;

    int beg = offsets[wid], end = offsets[wid + 1];
    float aldv = al_dst1[wid * 2 + head];

    float l = 0.f, p0 = 0.f, p1 = 0.f, p2 = 0.f, p3 = 0.f;

    int e = beg;
    for (; e + 3 < end; e += 4) {
        int sa = csr_src[e];
        int sb = csr_src[e + 1];
        int sc = csr_src[e + 2];
        int sd = csr_src[e + 3];
        float la = al_src1[sa * 2 + head] + aldv;
        float lb = al_src1[sb * 2 + head] + aldv;
        float lcv = al_src1[sc * 2 + head] + aldv;
        float ld = al_src1[sd * 2 + head] + aldv;
        ushort4 ha = *reinterpret_cast<const ushort4*>(h1 + (size_t)sa * 256 + ch);
        ushort4 hb = *reinterpret_cast<const ushort4*>(h1 + (size_t)sb * 256 + ch);
        ushort4 hc = *reinterpret_cast<const ushort4*>(h1 + (size_t)sc * 256 + ch);
        ushort4 hd = *reinterpret_cast<const ushort4*>(h1 + (size_t)sd * 256 + ch);
        float wa = __expf(lrelu(la));
        float wb = __expf(lrelu(lb));
        float wc = __expf(lrelu(lcv));
        float wd = __expf(lrelu(ld));
        p0 += wa * bf2f(ha.x) + wb * bf2f(hb.x) + wc * bf2f(hc.x) + wd * bf2f(hd.x);
        p1 += wa * bf2f(ha.y) + wb * bf2f(hb.y) + wc * bf2f(hc.y) + wd * bf2f(hd.y);
        p2 += wa * bf2f(ha.z) + wb * bf2f(hb.z) + wc * bf2f(hc.z) + wd * bf2f(hd.z);
        p3 += wa * bf2f(ha.w) + wb * bf2f(hb.w) + wc * bf2f(hc.w) + wd * bf2f(hd.w);
        l += (wa + wb) + (wc + wd);
    }
    for (; e < end; ++e) {
        int sa = csr_src[e];
        float la = al_src1[sa * 2 + head] + aldv;
        ushort4 ha = *reinterpret_cast<const ushort4*>(h1 + (size_t)sa * 256 + ch);
        float wa = __expf(lrelu(la));
        p0 += wa * bf2f(ha.x);
        p1 += wa * bf2f(ha.y);
        p2 += wa * bf2f(ha.z);
        p3 += wa * bf2f(ha.w);
        l += wa;
    }

    float inv = 1.f / l;
    float4 bb = *reinterpret_cast<const float4*>(b1 + ch);
    float r0 = fmaxf(p0 * inv + bb.x, 0.f);
    float r1 = fmaxf(p1 * inv + bb.y, 0.f);
    float r2 = fmaxf(p2 * inv + bb.z, 0.f);
    float r3 = fmaxf(p3 * inv + bb.w, 0.f);

    float4 w0 = *reinterpret_cast<const float4*>(W2 + (size_t)(ch + 0) * 4);
    float4 w1 = *reinterpret_cast<const float4*>(W2 + (size_t)(ch + 1) * 4);
    float4 w2 = *reinterpret_cast<const float4*>(W2 + (size_t)(ch + 2) * 4);
    float4 w3 = *reinterpret_cast<const float4*>(W2 + (size_t)(ch + 3) * 4);
    float g0 = r0 * w0.x + r1 * w1.x + r2 * w2.x + r3 * w3.x;
    float g1 = r0 * w0.y + r1 * w1.y + r2 * w2.y + r3 * w3.y;
    float g2v = r0 * w0.z + r1 * w1.z + r2 * w2.z + r3 * w3.z;
    float g3 = r0 * w0.w + r1 * w1.w + r2 * w2.w + r3 * w3.w;
#pragma unroll
    for (int mask = 32; mask >= 1; mask >>= 1) {
        g0 += __shfl_xor(g0, mask, 64);
        g1 += __shfl_xor(g1, mask, 64);
        g2v += __shfl_xor(g2v, mask, 64);
        g3 += __shfl_xor(g3, mask, 64);
    }
    if (lane == 0) {
        float4 gv;
        gv.x = g0; gv.y = g1; gv.z = g2v; gv.w = g3;
        *reinterpret_cast<float4*>(g2out + (size_t)wid * 4) = gv;
        al_src2o[wid] = g0 * a_src2[0] + g1 * a_src2[1] + g2v * a_src2[2] + g3 * a_src2[3];
        al_dst2o[wid] = g0 * a_dst2[0] + g1 * a_dst2[1] + g2v * a_dst2[2] + g3 * a_dst2[3];
    }
}

// ---------------- Layer 2 aggregation: THREAD per node (4 channels only) ----------------

__global__ __launch_bounds__(256) void agg2_kernel(
    const float* __restrict__ g2, const float* __restrict__ al_src2,
    const float* __restrict__ al_dst2, const int* __restrict__ offsets,
    const int* __restrict__ csr_src, const float* __restrict__ b2,
    float* __restrict__ out, int N) {
    int nid = blockIdx.x * 256 + threadIdx.x;
    if (nid >= N) return;

    int beg = offsets[nid], end = offsets[nid + 1];
    float aldv = al_dst2[nid];

    float l = 0.f, p0 = 0.f, p1 = 0.f, p2 = 0.f, p3 = 0.f;

    int e = beg;
    for (; e + 3 < end; e += 4) {
        int sa = csr_src[e];
        int sb = csr_src[e + 1];
        int sc = csr_src[e + 2];
        int sd = csr_src[e + 3];
        float la = al_src2[sa] + aldv;
        float lb = al_src2[sb] + aldv;
        float lcv = al_src2[sc] + aldv;
        float ld = al_src2[sd] + aldv;
        float4 ga = *reinterpret_cast<const float4*>(g2 + (size_t)sa * 4);
        float4 gb = *reinterpret_cast<const float4*>(g2 + (size_t)sb * 4);
        float4 gc = *reinterpret_cast<const float4*>(g2 + (size_t)sc * 4);
        float4 gd = *reinterpret_cast<const float4*>(g2 + (size_t)sd * 4);
        float wa = __expf(lrelu(la));
        float wb = __expf(lrelu(lb));
        float wc = __expf(lrelu(lcv));
        float wd = __expf(lrelu(ld));
        p0 += wa * ga.x + wb * gb.x + wc * gc.x + wd * gd.x;
        p1 += wa * ga.y + wb * gb.y + wc * gc.y + wd * gd.y;
        p2 += wa * ga.z + wb * gb.z + wc * gc.z + wd * gd.z;
        p3 += wa * ga.w + wb * gb.w + wc * gc.w + wd * gd.w;
        l += (wa + wb) + (wc + wd);
    }
    for (; e < end; ++e) {
        int sa = csr_src[e];
        float la = al_src2[sa] + aldv;
        float4 ga = *reinterpret_cast<const float4*>(g2 + (size_t)sa * 4);
        float wa = __expf(lrelu(la));
        p0 += wa * ga.x;
        p1 += wa * ga.y;
        p2 += wa * ga.z;
        p3 += wa * ga.w;
        l += wa;
    }

    float inv = 1.f / l;
    float r0 = p0 * inv + b2[0];
    float r1 = p1 * inv + b2[1];
    float r2 = p2 * inv + b2[2];
    float r3 = p3 * inv + b2[3];
    float mx = fmaxf(fmaxf(r0, r1), fmaxf(r2, r3));
    float s0 = __expf(r0 - mx), s1 = __expf(r1 - mx), s2 = __expf(r2 - mx), s3 = __expf(r3 - mx);
    float ls = __logf(s0 + s1 + s2 + s3);
    float4 ov;
    ov.x = r0 - mx - ls;
    ov.y = r1 - mx - ls;
    ov.z = r2 - mx - ls;
    ov.w = r3 - mx - ls;
    *reinterpret_cast<float4*>(out + (size_t)nid * 4) = ov;
}

// ---------------- host ----------------

extern "C" void kernel_launch(void* const* d_in, const int* in_sizes, int n_in,
                              void* d_out, int out_size, void* d_ws, size_t ws_size,
                              hipStream_t stream) {
    const float* x = (const float*)d_in[0];
    const int* edge_index = (const int*)d_in[1];
    const float* W1 = (const float*)d_in[2];
    const float* a_src1 = (const float*)d_in[3];
    const float* a_dst1 = (const float*)d_in[4];
    const float* b1 = (const float*)d_in[5];
    const float* W2 = (const float*)d_in[6];
    const float* a_src2 = (const float*)d_in[7];
    const float* a_dst2 = (const float*)d_in[8];
    const float* b2 = (const float*)d_in[9];
    float* out = (float*)d_out;

    const int N = in_sizes[0] / 256;
    const int E = in_sizes[1] / 2;
    const int EN = E + N;
    const int* src_idx = edge_index;
    const int* dst_idx = edge_index + E;

    char* ws = (char*)d_ws;
    size_t off = 0;
    auto alloc = [&](size_t bytes) -> char* {
        char* p = ws + off;
        off += (bytes + 255) & ~(size_t)255;
        return p;
    };
    unsigned short* h1 = (unsigned short*)alloc((size_t)N * 256 * 2);
    unsigned short* xs = (unsigned short*)alloc((size_t)N * 256 * 2);
    unsigned short* W1s = (unsigned short*)alloc((size_t)256 * 256 * 2);
    float* al_src1 = (float*)alloc((size_t)N * 2 * 4);
    float* al_dst1 = (float*)alloc((size_t)N * 2 * 4);
    float* g2 = (float*)alloc((size_t)N * 4 * 4);
    float* al_src2 = (float*)alloc((size_t)N * 4);
    float* al_dst2 = (float*)alloc((size_t)N * 4);
    int* offsets = (int*)alloc((size_t)(N + 1) * 4);
    int* cursor = (int*)alloc((size_t)N * 4);
    int* csr_src = (int*)alloc((size_t)EN * 4);
    int2* pairbuf = (int2*)alloc((size_t)EN * 8);
    int* bucketCursor = (int*)alloc(256 * 4);
    int* blockSums = (int*)alloc(128 * 4);

    hipMemsetAsync(cursor, 0, (size_t)N * 4, stream);

    prep_w1s<<<256, 256, 0, stream>>>(W1, W1s);
    int total8 = N * 32;  // N*256/8
    prep_xs<<<(total8 + 255) / 256, 256, 0, stream>>>(x, xs, total8);

    int hb = (EN + 255) / 256;
    hist_kernel<<<hb, 256, 0, stream>>>(dst_idx, cursor, E, N);

    int nb = (N + SCAN_ELEMS - 1) / SCAN_ELEMS;
    scan_blocks_kernel<<<nb, SCAN_TPB, 0, stream>>>(cursor, offsets, blockSums, N);
    scan_sums_kernel<<<1, 128, 0, stream>>>(blockSums, nb);
    scan_finalize_kernel<<<nb, SCAN_TPB, 0, stream>>>(offsets, blockSums, cursor, N, EN);

    int nbuck = (N + 511) >> 9;
    bucket_init_kernel<<<1, 256, 0, stream>>>(offsets, bucketCursor, nbuck, N);
    int binb = (EN + BIN_CHUNK - 1) / BIN_CHUNK;
    bin_kernel<<<binb, 256, 0, stream>>>(src_idx, dst_idx, bucketCursor, pairbuf, E, N);
    sortb_kernel<<<nbuck, 256, 0, stream>>>(pairbuf, offsets, cursor, csr_src, N);

    int gb = ((N + 63) / 64) * 2;  // x2 column halves
    gemm1_kernel<<<gb, 256, 0, stream>>>(xs, W1s, a_src1, a_dst1, h1, al_src1, al_dst1, N);

    int ab = (N + 3) / 4;
    agg1_kernel<<<ab, 256, 0, stream>>>(h1, al_src1, al_dst1, offsets, csr_src, b1, W2,
                                        a_src2, a_dst2, g2, al_src2, al_dst2, N);
    agg2_kernel<<<(N + 255) / 256, 256, 0, stream>>>(g2, al_src2, al_dst2, offsets, csr_src,
                                                     b2, out, N);
}